// Round 1
// baseline (2996.944 us; speedup 1.0000x reference)
//
#include <hip/hip_runtime.h>
#include <hip/hip_bf16.h>
#include <math.h>

// Problem constants (from reference)
#define NN 100000
#define FF 512
#define HH 256
#define CC 64
#define KHOPS 10
#define BN_EPS 1e-5f

// ---------------- utility kernels ----------------
__global__ void k_zero(float* p, int n) {
    int i = blockIdx.x * blockDim.x + threadIdx.x;
    if (i < n) p[i] = 0.f;
}

__global__ void k_deg_init(int* deg, int n) {
    int i = blockIdx.x * blockDim.x + threadIdx.x;
    if (i < n) deg[i] = 1;  // self-loop
}

__global__ void k_deg_count(const int* __restrict__ dst, int e, int* deg) {
    for (int i = blockIdx.x * blockDim.x + threadIdx.x; i < e; i += gridDim.x * blockDim.x)
        atomicAdd(&deg[dst[i]], 1);
}

__global__ void k_dis(const int* __restrict__ deg, float* dis, int n) {
    int i = blockIdx.x * blockDim.x + threadIdx.x;
    if (i < n) dis[i] = rsqrtf((float)deg[i]);
}

// single-block scan: offs = exclusive prefix of (deg-1); cursor = offs; offs[n]=E
__global__ void k_scan(const int* __restrict__ deg, int* offs, int* cursor, int n) {
    __shared__ int ls[1024];
    const int CHUNK = (NN + 1023) / 1024;  // 98
    int t = threadIdx.x;
    int start = t * CHUNK;
    int end = min(start + CHUNK, n);
    int s = 0;
    for (int i = start; i < end; i++) s += deg[i] - 1;
    ls[t] = s;
    __syncthreads();
    for (int d = 1; d < 1024; d <<= 1) {
        int v = (t >= d) ? ls[t - d] : 0;
        __syncthreads();
        ls[t] += v;
        __syncthreads();
    }
    int run = ls[t] - s;  // exclusive prefix
    for (int i = start; i < end; i++) {
        offs[i] = run;
        cursor[i] = run;
        run += deg[i] - 1;
    }
    if (t == 1023) offs[n] = ls[1023];
}

__global__ void k_fill(const int* __restrict__ src, const int* __restrict__ dst, int e,
                       const float* __restrict__ dis, int* cursor,
                       int* __restrict__ csrc, float* __restrict__ cw) {
    for (int i = blockIdx.x * blockDim.x + threadIdx.x; i < e; i += gridDim.x * blockDim.x) {
        int d = dst[i];
        int s = src[i];
        int p = atomicAdd(&cursor[d], 1);
        csrc[p] = s;
        cw[p] = dis[s] * dis[d];
    }
}

// ---------------- fp32 tiled GEMM: C = A[M,K] @ B[K,N] + bias ----------------
__global__ __launch_bounds__(256) void k_gemm_bias(
    const float* __restrict__ A, const float* __restrict__ B,
    const float* __restrict__ bias, float* __restrict__ C,
    int M, int Kd, int Nd) {
    __shared__ float As[16][64];
    __shared__ float Bs[16][64];
    int tid = threadIdx.x;
    int tx = tid & 15, ty = tid >> 4;
    int row_base = blockIdx.y * 64;
    int col_base = blockIdx.x * 64;
    float acc[4][4] = {};

    int ar = tid >> 2;        // 0..63 (A row within tile)
    int ak = (tid & 3) * 4;   // 0,4,8,12 (k offset)
    int bk = tid >> 4;        // 0..15
    int bn = (tid & 15) * 4;  // 0..60

    bool arow_ok = (row_base + ar) < M;
    const float* Aptr = A + (size_t)(row_base + ar) * Kd;

    for (int kt = 0; kt < Kd; kt += 16) {
        float4 av = arow_ok ? *(const float4*)(Aptr + kt + ak) : make_float4(0.f, 0.f, 0.f, 0.f);
        float4 bv = *(const float4*)(B + (size_t)(kt + bk) * Nd + col_base + bn);
        __syncthreads();
        As[ak + 0][ar] = av.x;
        As[ak + 1][ar] = av.y;
        As[ak + 2][ar] = av.z;
        As[ak + 3][ar] = av.w;
        *(float4*)&Bs[bk][bn] = bv;
        __syncthreads();
#pragma unroll
        for (int kk = 0; kk < 16; kk++) {
            float4 a = *(float4*)&As[kk][ty * 4];
            float4 b = *(float4*)&Bs[kk][tx * 4];
            acc[0][0] += a.x * b.x; acc[0][1] += a.x * b.y; acc[0][2] += a.x * b.z; acc[0][3] += a.x * b.w;
            acc[1][0] += a.y * b.x; acc[1][1] += a.y * b.y; acc[1][2] += a.y * b.z; acc[1][3] += a.y * b.w;
            acc[2][0] += a.z * b.x; acc[2][1] += a.z * b.y; acc[2][2] += a.z * b.z; acc[2][3] += a.z * b.w;
            acc[3][0] += a.w * b.x; acc[3][1] += a.w * b.y; acc[3][2] += a.w * b.z; acc[3][3] += a.w * b.w;
        }
    }
    int cb = col_base + tx * 4;
    float4 bb = *(const float4*)(bias + cb);
#pragma unroll
    for (int i = 0; i < 4; i++) {
        int r = row_base + ty * 4 + i;
        if (r < M) {
            float4 o;
            o.x = acc[i][0] + bb.x;
            o.y = acc[i][1] + bb.y;
            o.z = acc[i][2] + bb.z;
            o.w = acc[i][3] + bb.w;
            *(float4*)(C + (size_t)r * Nd + cb) = o;
        }
    }
}

// ---------------- BN stats + apply ----------------
__global__ void k_colstats(const float* __restrict__ h, float* sum, float* sumsq, int n) {
    int c = threadIdx.x;  // 256 columns
    float s = 0.f, s2 = 0.f;
    for (int r = blockIdx.x; r < n; r += gridDim.x) {
        float v = h[(size_t)r * HH + c];
        s += v;
        s2 += v * v;
    }
    atomicAdd(&sum[c], s);
    atomicAdd(&sumsq[c], s2);
}

__global__ void k_bnrelu(float* h, const float* __restrict__ g, const float* __restrict__ be,
                         const float* __restrict__ sum, const float* __restrict__ sumsq, int n) {
    size_t total = (size_t)n * HH;
    for (size_t idx = (size_t)blockIdx.x * blockDim.x + threadIdx.x; idx < total;
         idx += (size_t)gridDim.x * blockDim.x) {
        int c = (int)(idx & (HH - 1));
        float mu = sum[c] * (1.f / NN);
        float var = sumsq[c] * (1.f / NN) - mu * mu;
        float v = (h[idx] - mu) * rsqrtf(var + BN_EPS) * g[c] + be[c];
        h[idx] = fmaxf(v, 0.f);
    }
}

// ---------------- propagation ----------------
__device__ inline float wred_sum(float v) {
#pragma unroll
    for (int m = 32; m >= 1; m >>= 1) v += __shfl_xor(v, m);
    return v;
}
__device__ inline float wred_max(float v) {
#pragma unroll
    for (int m = 32; m >= 1; m >>= 1) v = fmaxf(v, __shfl_xor(v, m));
    return v;
}

__global__ void k_prescore(const float* __restrict__ h2, const float* __restrict__ pw,
                           const float* __restrict__ pbp, float* __restrict__ acc, int n) {
    int wid = (int)((blockIdx.x * (size_t)blockDim.x + threadIdx.x) >> 6);
    int lane = threadIdx.x & 63;
    if (wid >= n) return;
    float v = h2[(size_t)wid * CC + lane];
    float d = wred_sum(v * pw[lane]);
    float s = 1.f / (1.f + expf(-(d + pbp[0])));
    acc[(size_t)wid * CC + lane] = s * v;
}

__global__ void k_hop(const float* __restrict__ xin, float* __restrict__ xout,
                      float* __restrict__ acc, const int* __restrict__ offs,
                      const int* __restrict__ csrc, const float* __restrict__ cw,
                      const float* __restrict__ dis, const float* __restrict__ pw,
                      const float* __restrict__ pbp, int n) {
    int wid = (int)((blockIdx.x * (size_t)blockDim.x + threadIdx.x) >> 6);
    int lane = threadIdx.x & 63;
    if (wid >= n) return;
    float dn = dis[wid];
    float y = dn * dn * xin[(size_t)wid * CC + lane];
    int p0 = offs[wid], p1 = offs[wid + 1];
    for (int p = p0; p < p1; p++) {
        int s = csrc[p];
        float w = cw[p];
        y += w * xin[(size_t)s * CC + lane];
    }
    xout[(size_t)wid * CC + lane] = y;
    float d = wred_sum(y * pw[lane]);
    float sc = 1.f / (1.f + expf(-(d + pbp[0])));
    acc[(size_t)wid * CC + lane] += sc * y;
}

__global__ void k_logsoftmax(const float* __restrict__ acc, float* __restrict__ out, int n) {
    int wid = (int)((blockIdx.x * (size_t)blockDim.x + threadIdx.x) >> 6);
    int lane = threadIdx.x & 63;
    if (wid >= n) return;
    float v = acc[(size_t)wid * CC + lane];
    float m = wred_max(v);
    float e = expf(v - m);
    float s = wred_sum(e);
    out[(size_t)wid * CC + lane] = v - m - logf(s);
}

// ---------------- launch ----------------
extern "C" void kernel_launch(void* const* d_in, const int* in_sizes, int n_in,
                              void* d_out, int out_size, void* d_ws, size_t ws_size,
                              hipStream_t stream) {
    const float* x  = (const float*)d_in[0];
    const float* W0 = (const float*)d_in[1];
    const float* b0 = (const float*)d_in[2];
    const float* g0 = (const float*)d_in[3];
    const float* be0 = (const float*)d_in[4];
    const float* W1 = (const float*)d_in[5];
    const float* b1 = (const float*)d_in[6];
    const float* g1 = (const float*)d_in[7];
    const float* be1 = (const float*)d_in[8];
    const float* W2 = (const float*)d_in[9];
    const float* b2 = (const float*)d_in[10];
    const float* pw = (const float*)d_in[11];
    const float* pb = (const float*)d_in[12];
    const int* ei = (const int*)d_in[13];
    const int E = in_sizes[13] / 2;
    const int* esrc = ei;
    const int* edst = ei + E;

    char* ws = (char*)d_ws;
    float* h0   = (float*)(ws + 0);              // 102,400,000 B  [N,256]
    float* h1   = (float*)(ws + 102400000);      // 102,400,000 B  [N,256]
    int*   deg  = (int*)  (ws + 204800000);      // 400,000 B
    float* dis  = (float*)(ws + 205200000);      // 400,000 B
    int*   offs = (int*)  (ws + 205600000);      // 400,004 B
    int*   cur  = (int*)  (ws + 206000256);      // 400,000 B
    int*   csrc = (int*)  (ws + 206400256);      // 6,400,000 B
    float* cw   = (float*)(ws + 212800256);      // 6,400,000 B
    float* stats = (float*)(ws + 219200256);     // 4 KiB (sum0,sq0,sum1,sq1)
    // aliases after producers are dead:
    float* h2  = h0;                              // [N,64] (h0 dead after gemm2)
    float* xa  = h1;                              // [N,64] (h1 dead after gemm3)
    float* xb  = (float*)(ws + 102400000 + 25600000);
    float* acc = (float*)(ws + 102400000 + 51200000);

    float* sum0 = stats, *sq0 = stats + 256, *sum1 = stats + 512, *sq1 = stats + 768;

    float* out = (float*)d_out;

    const int TPB = 256;
    int ngrid = (NN + TPB - 1) / TPB;
    int egrid = (E + TPB - 1) / TPB;
    int wgrid = (NN * 64 + TPB - 1) / TPB;  // one wave per node

    // graph preprocessing
    hipLaunchKernelGGL(k_zero, dim3(1), dim3(1024), 0, stream, stats, 1024);
    hipLaunchKernelGGL(k_deg_init, dim3(ngrid), dim3(TPB), 0, stream, deg, NN);
    hipLaunchKernelGGL(k_deg_count, dim3(egrid), dim3(TPB), 0, stream, edst, E, deg);
    hipLaunchKernelGGL(k_dis, dim3(ngrid), dim3(TPB), 0, stream, deg, dis, NN);
    hipLaunchKernelGGL(k_scan, dim3(1), dim3(1024), 0, stream, deg, offs, cur, NN);
    hipLaunchKernelGGL(k_fill, dim3(egrid), dim3(TPB), 0, stream, esrc, edst, E, dis, cur, csrc, cw);

    // layer 0
    hipLaunchKernelGGL(k_gemm_bias, dim3(HH / 64, (NN + 63) / 64), dim3(256), 0, stream,
                       x, W0, b0, h0, NN, FF, HH);
    hipLaunchKernelGGL(k_colstats, dim3(256), dim3(256), 0, stream, h0, sum0, sq0, NN);
    hipLaunchKernelGGL(k_bnrelu, dim3(4096), dim3(256), 0, stream, h0, g0, be0, sum0, sq0, NN);
    // layer 1
    hipLaunchKernelGGL(k_gemm_bias, dim3(HH / 64, (NN + 63) / 64), dim3(256), 0, stream,
                       h0, W1, b1, h1, NN, HH, HH);
    hipLaunchKernelGGL(k_colstats, dim3(256), dim3(256), 0, stream, h1, sum1, sq1, NN);
    hipLaunchKernelGGL(k_bnrelu, dim3(4096), dim3(256), 0, stream, h1, g1, be1, sum1, sq1, NN);
    // layer 2 (logits) -> h2 (reuses h0 space)
    hipLaunchKernelGGL(k_gemm_bias, dim3(CC / 64, (NN + 63) / 64), dim3(256), 0, stream,
                       h1, W2, b2, h2, NN, HH, CC);

    // propagation with online score accumulation
    hipLaunchKernelGGL(k_prescore, dim3(wgrid), dim3(TPB), 0, stream, h2, pw, pb, acc, NN);
    const float* curx = h2;
    float* bufs[2] = {xa, xb};
    for (int k = 0; k < KHOPS; k++) {
        float* nxt = bufs[k & 1];
        hipLaunchKernelGGL(k_hop, dim3(wgrid), dim3(TPB), 0, stream,
                           curx, nxt, acc, offs, csrc, cw, dis, pw, pb, NN);
        curx = nxt;
    }

    hipLaunchKernelGGL(k_logsoftmax, dim3(wgrid), dim3(TPB), 0, stream, acc, out, NN);
}

// Round 2
// 2425.228 us; speedup vs baseline: 1.2357x; 1.2357x over previous
//
#include <hip/hip_runtime.h>
#include <hip/hip_bf16.h>
#include <math.h>

// Problem constants (from reference)
#define NN 100000
#define FF 512
#define HH 256
#define CC 64
#define KHOPS 10
#define BN_EPS 1e-5f

typedef __bf16 bf16x8 __attribute__((ext_vector_type(8)));
typedef float f32x4 __attribute__((ext_vector_type(4)));
typedef unsigned short ushort8v __attribute__((ext_vector_type(8)));
typedef unsigned short ushort4v __attribute__((ext_vector_type(4)));

__device__ __forceinline__ unsigned short f2bf(float f) {
    unsigned u = __builtin_bit_cast(unsigned, f);
    u += 0x7FFFu + ((u >> 16) & 1u);  // RNE
    return (unsigned short)(u >> 16);
}
__device__ __forceinline__ float bf2f(unsigned short h) {
    unsigned u = ((unsigned)h) << 16;
    return __builtin_bit_cast(float, u);
}

// ---------------- utility kernels ----------------
__global__ void k_zero(float* p, int n) {
    int i = blockIdx.x * blockDim.x + threadIdx.x;
    if (i < n) p[i] = 0.f;
}

__global__ void k_deg_init(int* deg, int n) {
    int i = blockIdx.x * blockDim.x + threadIdx.x;
    if (i < n) deg[i] = 1;  // self-loop
}

__global__ void k_deg_count(const int* __restrict__ dst, int e, int* deg) {
    for (int i = blockIdx.x * blockDim.x + threadIdx.x; i < e; i += gridDim.x * blockDim.x)
        atomicAdd(&deg[dst[i]], 1);
}

__global__ void k_dis(const int* __restrict__ deg, float* dis, int n) {
    int i = blockIdx.x * blockDim.x + threadIdx.x;
    if (i < n) dis[i] = rsqrtf((float)deg[i]);
}

// single-block scan: offs = exclusive prefix of (deg-1); cursor = offs; offs[n]=E
__global__ void k_scan(const int* __restrict__ deg, int* offs, int* cursor, int n) {
    __shared__ int ls[1024];
    const int CHUNK = (NN + 1023) / 1024;  // 98
    int t = threadIdx.x;
    int start = t * CHUNK;
    int end = min(start + CHUNK, n);
    int s = 0;
    for (int i = start; i < end; i++) s += deg[i] - 1;
    ls[t] = s;
    __syncthreads();
    for (int d = 1; d < 1024; d <<= 1) {
        int v = (t >= d) ? ls[t - d] : 0;
        __syncthreads();
        ls[t] += v;
        __syncthreads();
    }
    int run = ls[t] - s;  // exclusive prefix
    for (int i = start; i < end; i++) {
        offs[i] = run;
        cursor[i] = run;
        run += deg[i] - 1;
    }
    if (t == 1023) offs[n] = ls[1023];
}

__global__ void k_fill(const int* __restrict__ src, const int* __restrict__ dst, int e,
                       const float* __restrict__ dis, int* cursor,
                       int* __restrict__ csrc, float* __restrict__ cw) {
    for (int i = blockIdx.x * blockDim.x + threadIdx.x; i < e; i += gridDim.x * blockDim.x) {
        int d = dst[i];
        int s = src[i];
        int p = atomicAdd(&cursor[d], 1);
        csrc[p] = s;
        cw[p] = dis[s] * dis[d];
    }
}

// transpose+cast weights: Wt[n*K+k] = bf16(W[k*N+n])
__global__ void k_wt(const float* __restrict__ W, unsigned short* __restrict__ Wt,
                     int K, int N) {
    int i = blockIdx.x * blockDim.x + threadIdx.x;
    if (i < K * N) {
        int n = i / K;
        int k = i - n * K;
        Wt[i] = f2bf(W[(size_t)k * N + n]);
    }
}

// ---------------- bf16 MFMA GEMM ----------------
// C[M,Nd] = A[M,K] @ Bt[Nd,K]^T + bias.  BM=128, BN_=128 or 64, BK=32.
// 256 thr = 4 waves (2x2), per-wave 64 x (BN_/2) via 4 x NREP 16x16x32 MFMA frags.
template <int AF32, int BN_, int OUTBF>
__global__ __launch_bounds__(256) void k_gemm_mfma(
    const void* __restrict__ Av, const unsigned short* __restrict__ Bt,
    const float* __restrict__ bias, void* __restrict__ Cv,
    int M, int K, int Nd) {
    constexpr int NREP = BN_ / 32;
    __shared__ unsigned short Asb[128 * 32];
    __shared__ unsigned short Bsb[BN_ * 32];
    const int tid = threadIdx.x;
    const int lane = tid & 63;
    const int wid = tid >> 6;
    const int wrow = wid >> 1, wcol = wid & 1;
    const int row_base = blockIdx.y * 128;
    const int col_base = blockIdx.x * BN_;

    const float* Af = (const float*)Av;
    const unsigned short* Ab = (const unsigned short*)Av;

    f32x4 acc[4][NREP];
#pragma unroll
    for (int m = 0; m < 4; m++)
#pragma unroll
        for (int n = 0; n < NREP; n++)
#pragma unroll
            for (int j = 0; j < 4; j++) acc[m][n][j] = 0.f;

    for (int kt = 0; kt < K; kt += 32) {
        __syncthreads();
        // stage A tile [128][32] bf16, linear LDS: byte offset = e*16
#pragma unroll
        for (int i = 0; i < 2; ++i) {
            int e = tid + i * 256;
            int row = e >> 2, c = e & 3;
            int grow = row_base + row;
            ushort8v v = {0, 0, 0, 0, 0, 0, 0, 0};
            if (grow < M) {
                if (AF32) {
                    const float* p = Af + (size_t)grow * K + kt + c * 8;
                    float4 f0 = *(const float4*)p;
                    float4 f1 = *(const float4*)(p + 4);
                    v[0] = f2bf(f0.x); v[1] = f2bf(f0.y); v[2] = f2bf(f0.z); v[3] = f2bf(f0.w);
                    v[4] = f2bf(f1.x); v[5] = f2bf(f1.y); v[6] = f2bf(f1.z); v[7] = f2bf(f1.w);
                } else {
                    v = *(const ushort8v*)(Ab + (size_t)grow * K + kt + c * 8);
                }
            }
            *(ushort8v*)(Asb + e * 8) = v;
        }
        // stage B tile [BN_][32] bf16 from Bt[N,K]
#pragma unroll
        for (int i = 0; i < BN_ / 64; ++i) {
            int e = tid + i * 256;
            int n = e >> 2, c = e & 3;
            ushort8v v = *(const ushort8v*)(Bt + (size_t)(col_base + n) * K + kt + c * 8);
            *(ushort8v*)(Bsb + e * 8) = v;
        }
        __syncthreads();
        // fragments: lane l holds elems k=(l>>4)*8+j of row/col (l&15)
        bf16x8 af[4], bfr[NREP];
#pragma unroll
        for (int m = 0; m < 4; ++m)
            af[m] = *(const bf16x8*)(Asb + (wrow * 64 + m * 16 + (lane & 15)) * 32 + (lane >> 4) * 8);
#pragma unroll
        for (int n = 0; n < NREP; ++n)
            bfr[n] = *(const bf16x8*)(Bsb + (wcol * (BN_ / 2) + n * 16 + (lane & 15)) * 32 + (lane >> 4) * 8);
#pragma unroll
        for (int m = 0; m < 4; ++m)
#pragma unroll
            for (int n = 0; n < NREP; ++n)
                acc[m][n] = __builtin_amdgcn_mfma_f32_16x16x32_bf16(af[m], bfr[n], acc[m][n], 0, 0, 0);
    }
    // epilogue: C/D mapping col=lane&15, row=(lane>>4)*4+j  (m89-verified)
    const int lc = lane & 15;
    const int lr = (lane >> 4) * 4;
#pragma unroll
    for (int m = 0; m < 4; ++m) {
        int gr0 = row_base + wrow * 64 + m * 16 + lr;
#pragma unroll
        for (int n = 0; n < NREP; ++n) {
            int gc = col_base + wcol * (BN_ / 2) + n * 16 + lc;
            float bb = bias[gc];
#pragma unroll
            for (int j = 0; j < 4; ++j) {
                int gr = gr0 + j;
                if (gr < M) {
                    float v = acc[m][n][j] + bb;
                    if (OUTBF)
                        ((unsigned short*)Cv)[(size_t)gr * Nd + gc] = f2bf(v);
                    else
                        ((float*)Cv)[(size_t)gr * Nd + gc] = v;
                }
            }
        }
    }
}

// ---------------- BN stats + apply (bf16 activations) ----------------
__global__ void k_colstats_bf(const unsigned short* __restrict__ h, float* sum, float* sumsq, int n) {
    int c = threadIdx.x;  // 256 columns
    float s = 0.f, s2 = 0.f;
    for (int r = blockIdx.x; r < n; r += gridDim.x) {
        float v = bf2f(h[(size_t)r * HH + c]);
        s += v;
        s2 += v * v;
    }
    atomicAdd(&sum[c], s);
    atomicAdd(&sumsq[c], s2);
}

__global__ void k_bnfin(const float* __restrict__ sum, const float* __restrict__ sq,
                        const float* __restrict__ g, const float* __restrict__ be,
                        float* scale, float* shift) {
    int c = threadIdx.x;
    float mu = sum[c] * (1.f / NN);
    float var = sq[c] * (1.f / NN) - mu * mu;
    float sc = g[c] * rsqrtf(var + BN_EPS);
    scale[c] = sc;
    shift[c] = be[c] - mu * sc;
}

__global__ void k_bnrelu_bf(unsigned short* h, const float* __restrict__ scale,
                            const float* __restrict__ shift, int n) {
    int total = n * (HH / 4);
    for (int idx = blockIdx.x * blockDim.x + threadIdx.x; idx < total;
         idx += gridDim.x * blockDim.x) {
        int c4 = (idx & (HH / 4 - 1)) * 4;
        ushort4v v = *(ushort4v*)(h + (size_t)idx * 4);
#pragma unroll
        for (int j = 0; j < 4; j++) {
            float f = bf2f(v[j]);
            f = fmaxf(f * scale[c4 + j] + shift[c4 + j], 0.f);
            v[j] = f2bf(f);
        }
        *(ushort4v*)(h + (size_t)idx * 4) = v;
    }
}

// ---------------- propagation ----------------
__device__ inline float wred_sum(float v) {
#pragma unroll
    for (int m = 32; m >= 1; m >>= 1) v += __shfl_xor(v, m);
    return v;
}
__device__ inline float wred_max(float v) {
#pragma unroll
    for (int m = 32; m >= 1; m >>= 1) v = fmaxf(v, __shfl_xor(v, m));
    return v;
}

__global__ void k_prescore(const float* __restrict__ h2, const float* __restrict__ pw,
                           const float* __restrict__ pbp, float* __restrict__ acc, int n) {
    int wid = (int)((blockIdx.x * (size_t)blockDim.x + threadIdx.x) >> 6);
    int lane = threadIdx.x & 63;
    if (wid >= n) return;
    float v = h2[(size_t)wid * CC + lane];
    float d = wred_sum(v * pw[lane]);
    float s = 1.f / (1.f + expf(-(d + pbp[0])));
    acc[(size_t)wid * CC + lane] = s * v;
}

__global__ void k_hop(const float* __restrict__ xin, float* __restrict__ xout,
                      float* __restrict__ acc, const int* __restrict__ offs,
                      const int* __restrict__ csrc, const float* __restrict__ cw,
                      const float* __restrict__ dis, const float* __restrict__ pw,
                      const float* __restrict__ pbp, int n) {
    int wid = (int)((blockIdx.x * (size_t)blockDim.x + threadIdx.x) >> 6);
    int lane = threadIdx.x & 63;
    if (wid >= n) return;
    float dn = dis[wid];
    float y = dn * dn * xin[(size_t)wid * CC + lane];
    int p0 = offs[wid], p1 = offs[wid + 1];
    for (int p = p0; p < p1; p++) {
        int s = csrc[p];
        float w = cw[p];
        y += w * xin[(size_t)s * CC + lane];
    }
    xout[(size_t)wid * CC + lane] = y;
    float d = wred_sum(y * pw[lane]);
    float sc = 1.f / (1.f + expf(-(d + pbp[0])));
    acc[(size_t)wid * CC + lane] += sc * y;
}

__global__ void k_logsoftmax(const float* __restrict__ acc, float* __restrict__ out, int n) {
    int wid = (int)((blockIdx.x * (size_t)blockDim.x + threadIdx.x) >> 6);
    int lane = threadIdx.x & 63;
    if (wid >= n) return;
    float v = acc[(size_t)wid * CC + lane];
    float m = wred_max(v);
    float e = expf(v - m);
    float s = wred_sum(e);
    out[(size_t)wid * CC + lane] = v - m - logf(s);
}

// ---------------- launch ----------------
extern "C" void kernel_launch(void* const* d_in, const int* in_sizes, int n_in,
                              void* d_out, int out_size, void* d_ws, size_t ws_size,
                              hipStream_t stream) {
    const float* x  = (const float*)d_in[0];
    const float* W0 = (const float*)d_in[1];
    const float* b0 = (const float*)d_in[2];
    const float* g0 = (const float*)d_in[3];
    const float* be0 = (const float*)d_in[4];
    const float* W1 = (const float*)d_in[5];
    const float* b1 = (const float*)d_in[6];
    const float* g1 = (const float*)d_in[7];
    const float* be1 = (const float*)d_in[8];
    const float* W2 = (const float*)d_in[9];
    const float* b2 = (const float*)d_in[10];
    const float* pw = (const float*)d_in[11];
    const float* pb = (const float*)d_in[12];
    const int* ei = (const int*)d_in[13];
    const int E = in_sizes[13] / 2;
    const int* esrc = ei;
    const int* edst = ei + E;

    char* ws = (char*)d_ws;
    unsigned short* h0b = (unsigned short*)(ws + 0);           // [N,256] bf16  51.2MB
    unsigned short* h1b = (unsigned short*)(ws + 51200000);    // [N,256] bf16  51.2MB
    float* h2  = (float*)(ws + 102400000);                     // [N,64] f32    25.6MB
    float* xa  = (float*)(ws + 128000000);
    float* xb  = (float*)(ws + 153600000);
    float* acc = (float*)(ws + 179200000);
    int*   deg  = (int*)  (ws + 204800000);
    float* dis  = (float*)(ws + 205200000);
    int*   offs = (int*)  (ws + 205600000);
    int*   cur  = (int*)  (ws + 206000256);
    int*   csrc = (int*)  (ws + 206400256);
    float* cw   = (float*)(ws + 212800256);
    float* stats = (float*)(ws + 219200256);                   // 2048 floats
    unsigned short* W0t = (unsigned short*)(ws + 219208448);   // [256,512]
    unsigned short* W1t = (unsigned short*)(ws + 219470592);   // [256,256]
    unsigned short* W2t = (unsigned short*)(ws + 219601664);   // [64,256]

    float* sum0 = stats, *sq0 = stats + 256;
    float* sum1 = stats + 512, *sq1 = stats + 768;
    float* scale0 = stats + 1024, *shift0 = stats + 1280;
    float* scale1 = stats + 1536, *shift1 = stats + 1792;

    float* out = (float*)d_out;

    const int TPB = 256;
    int ngrid = (NN + TPB - 1) / TPB;
    int egrid = (E + TPB - 1) / TPB;
    int wgrid = (NN * 64 + TPB - 1) / TPB;  // one wave per node
    int mtiles = (NN + 127) / 128;          // 782

    // graph preprocessing
    k_zero<<<1, 1024, 0, stream>>>(stats, 1024);
    k_deg_init<<<ngrid, TPB, 0, stream>>>(deg, NN);
    k_deg_count<<<egrid, TPB, 0, stream>>>(edst, E, deg);
    k_dis<<<ngrid, TPB, 0, stream>>>(deg, dis, NN);
    k_scan<<<1, 1024, 0, stream>>>(deg, offs, cur, NN);
    k_fill<<<egrid, TPB, 0, stream>>>(esrc, edst, E, dis, cur, csrc, cw);

    // weight transpose+cast (tiny)
    k_wt<<<(FF * HH + TPB - 1) / TPB, TPB, 0, stream>>>(W0, W0t, FF, HH);
    k_wt<<<(HH * HH + TPB - 1) / TPB, TPB, 0, stream>>>(W1, W1t, HH, HH);
    k_wt<<<(HH * CC + TPB - 1) / TPB, TPB, 0, stream>>>(W2, W2t, HH, CC);

    // layer 0: x(f32) @ W0 -> h0b (bf16), fused cast in A-staging
    k_gemm_mfma<1, 128, 1><<<dim3(HH / 128, mtiles), 256, 0, stream>>>(
        x, W0t, b0, h0b, NN, FF, HH);
    k_colstats_bf<<<256, 256, 0, stream>>>(h0b, sum0, sq0, NN);
    k_bnfin<<<1, 256, 0, stream>>>(sum0, sq0, g0, be0, scale0, shift0);
    k_bnrelu_bf<<<4096, TPB, 0, stream>>>(h0b, scale0, shift0, NN);

    // layer 1: h0b(bf16) @ W1 -> h1b (bf16)
    k_gemm_mfma<0, 128, 1><<<dim3(HH / 128, mtiles), 256, 0, stream>>>(
        h0b, W1t, b1, h1b, NN, HH, HH);
    k_colstats_bf<<<256, 256, 0, stream>>>(h1b, sum1, sq1, NN);
    k_bnfin<<<1, 256, 0, stream>>>(sum1, sq1, g1, be1, scale1, shift1);
    k_bnrelu_bf<<<4096, TPB, 0, stream>>>(h1b, scale1, shift1, NN);

    // layer 2: h1b(bf16) @ W2 -> h2 (f32 logits)
    k_gemm_mfma<0, 64, 0><<<dim3(CC / 64, mtiles), 256, 0, stream>>>(
        h1b, W2t, b2, h2, NN, HH, CC);

    // propagation with online score accumulation
    k_prescore<<<wgrid, TPB, 0, stream>>>(h2, pw, pb, acc, NN);
    const float* curx = h2;
    float* bufs[2] = {xa, xb};
    for (int k = 0; k < KHOPS; k++) {
        float* nxt = bufs[k & 1];
        k_hop<<<wgrid, TPB, 0, stream>>>(curx, nxt, acc, offs, csrc, cw, dis, pw, pb, NN);
        curx = nxt;
    }

    k_logsoftmax<<<wgrid, TPB, 0, stream>>>(acc, out, NN);
}

// Round 3
// 1176.192 us; speedup vs baseline: 2.5480x; 2.0619x over previous
//
#include <hip/hip_runtime.h>
#include <hip/hip_bf16.h>
#include <math.h>

// Problem constants (from reference)
#define NN 100000
#define FF 512
#define HH 256
#define CC 64
#define KHOPS 10
#define BN_EPS 1e-5f

typedef __bf16 bf16x8 __attribute__((ext_vector_type(8)));
typedef float f32x4 __attribute__((ext_vector_type(4)));
typedef unsigned short ushort8v __attribute__((ext_vector_type(8)));

__device__ __forceinline__ unsigned short f2bf(float f) {
    unsigned u = __builtin_bit_cast(unsigned, f);
    u += 0x7FFFu + ((u >> 16) & 1u);  // RNE
    return (unsigned short)(u >> 16);
}
__device__ __forceinline__ float bf2f(unsigned short h) {
    unsigned u = ((unsigned)h) << 16;
    return __builtin_bit_cast(float, u);
}

// ---------------- utility kernels ----------------
__global__ void k_zero(float* p, int n) {
    int i = blockIdx.x * blockDim.x + threadIdx.x;
    if (i < n) p[i] = 0.f;
}

__global__ void k_deg_init(int* deg, int n) {
    int i = blockIdx.x * blockDim.x + threadIdx.x;
    if (i < n) deg[i] = 1;  // self-loop
}

__global__ void k_deg_count(const int* __restrict__ dst, int e, int* deg) {
    for (int i = blockIdx.x * blockDim.x + threadIdx.x; i < e; i += gridDim.x * blockDim.x)
        atomicAdd(&deg[dst[i]], 1);
}

__global__ void k_dis(const int* __restrict__ deg, float* dis, int n) {
    int i = blockIdx.x * blockDim.x + threadIdx.x;
    if (i < n) dis[i] = rsqrtf((float)deg[i]);
}

// ---------------- hierarchical scan: offs = exclusive prefix of (deg-1) ----------------
#define SCAN_B 1024
#define SCAN_NB ((NN + SCAN_B - 1) / SCAN_B)  // 98

__global__ void k_scan1(const int* __restrict__ deg, int* __restrict__ part, int n) {
    __shared__ int ls[SCAN_B];
    int i = blockIdx.x * SCAN_B + threadIdx.x;
    ls[threadIdx.x] = (i < n) ? deg[i] - 1 : 0;
    __syncthreads();
    for (int d = SCAN_B / 2; d > 0; d >>= 1) {
        if (threadIdx.x < d) ls[threadIdx.x] += ls[threadIdx.x + d];
        __syncthreads();
    }
    if (threadIdx.x == 0) part[blockIdx.x] = ls[0];
}

__global__ void k_scan2(int* part, int* offs_last, int nb) {
    if (threadIdx.x == 0) {
        int run = 0;
        for (int b = 0; b < nb; b++) { int v = part[b]; part[b] = run; run += v; }
        offs_last[0] = run;  // == E
    }
}

__global__ void k_scan3(const int* __restrict__ deg, const int* __restrict__ part,
                        int* __restrict__ offs, int* __restrict__ cur, int n) {
    __shared__ int ls[SCAN_B];
    int i = blockIdx.x * SCAN_B + threadIdx.x;
    int v = (i < n) ? deg[i] - 1 : 0;
    ls[threadIdx.x] = v;
    __syncthreads();
    for (int d = 1; d < SCAN_B; d <<= 1) {
        int t = (threadIdx.x >= d) ? ls[threadIdx.x - d] : 0;
        __syncthreads();
        ls[threadIdx.x] += t;
        __syncthreads();
    }
    if (i < n) {
        int ex = part[blockIdx.x] + ls[threadIdx.x] - v;
        offs[i] = ex;
        cur[i] = ex;
    }
}

__global__ void k_fill(const int* __restrict__ src, const int* __restrict__ dst, int e,
                       const float* __restrict__ dis, int* cursor,
                       int* __restrict__ csrc, float* __restrict__ cw) {
    for (int i = blockIdx.x * blockDim.x + threadIdx.x; i < e; i += gridDim.x * blockDim.x) {
        int d = dst[i];
        int s = src[i];
        int p = atomicAdd(&cursor[d], 1);
        csrc[p] = s;
        cw[p] = dis[s] * dis[d];
    }
}

// transpose+cast weights: Wt[n*K+k] = bf16(W[k*N+n])
__global__ void k_wt(const float* __restrict__ W, unsigned short* __restrict__ Wt,
                     int K, int N) {
    int i = blockIdx.x * blockDim.x + threadIdx.x;
    if (i < K * N) {
        int n = i / K;
        int k = i - n * K;
        Wt[i] = f2bf(W[(size_t)k * N + n]);
    }
}

// ---------------- bf16 MFMA GEMM with fused BN (input-side) + stats (output-side) ----
// C[M,Nd](bf16) = act(A) @ Bt^T + bias.  BM=128, BK=32, 4 waves (2x2).
// AF32: A is f32 (cast during staging). FUSEBN: A is bf16 pre-BN -> apply
// scale/shift + ReLU during staging. STATS: accumulate column sum/sumsq of
// (acc+bias) into global atomics (for the NEXT layer's BN).
template <int AF32, int BN_, int FUSEBN, int STATS>
__global__ __launch_bounds__(256) void k_gemm_mfma(
    const void* __restrict__ Av, const unsigned short* __restrict__ Bt,
    const float* __restrict__ bias, unsigned short* __restrict__ Cb,
    const float* __restrict__ bnscale, const float* __restrict__ bnshift,
    float* __restrict__ sum, float* __restrict__ sumsq,
    int M, int K, int Nd) {
    constexpr int NREP = BN_ / 32;
    __shared__ unsigned short Asb[128 * 32];
    __shared__ unsigned short Bsb[BN_ * 32];
    const int tid = threadIdx.x;
    const int lane = tid & 63;
    const int wid = tid >> 6;
    const int wrow = wid >> 1, wcol = wid & 1;
    const int row_base = blockIdx.y * 128;
    const int col_base = blockIdx.x * BN_;

    const float* Af = (const float*)Av;
    const unsigned short* Ab = (const unsigned short*)Av;

    f32x4 acc[4][NREP];
#pragma unroll
    for (int m = 0; m < 4; m++)
#pragma unroll
        for (int n = 0; n < NREP; n++)
#pragma unroll
            for (int j = 0; j < 4; j++) acc[m][n][j] = 0.f;

    for (int kt = 0; kt < K; kt += 32) {
        __syncthreads();
        // stage A tile [128][32] bf16, linear LDS
#pragma unroll
        for (int i = 0; i < 2; ++i) {
            int e = tid + i * 256;
            int row = e >> 2, c = e & 3;
            int grow = row_base + row;
            int kc = kt + c * 8;
            ushort8v v = {0, 0, 0, 0, 0, 0, 0, 0};
            if (grow < M) {
                if (AF32) {
                    const float* p = Af + (size_t)grow * K + kc;
                    float4 f0 = *(const float4*)p;
                    float4 f1 = *(const float4*)(p + 4);
                    v[0] = f2bf(f0.x); v[1] = f2bf(f0.y); v[2] = f2bf(f0.z); v[3] = f2bf(f0.w);
                    v[4] = f2bf(f1.x); v[5] = f2bf(f1.y); v[6] = f2bf(f1.z); v[7] = f2bf(f1.w);
                } else if (FUSEBN) {
                    ushort8v r = *(const ushort8v*)(Ab + (size_t)grow * K + kc);
                    float4 sc0 = *(const float4*)(bnscale + kc);
                    float4 sc1 = *(const float4*)(bnscale + kc + 4);
                    float4 sh0 = *(const float4*)(bnshift + kc);
                    float4 sh1 = *(const float4*)(bnshift + kc + 4);
                    float t0 = fmaxf(bf2f(r[0]) * sc0.x + sh0.x, 0.f);
                    float t1 = fmaxf(bf2f(r[1]) * sc0.y + sh0.y, 0.f);
                    float t2 = fmaxf(bf2f(r[2]) * sc0.z + sh0.z, 0.f);
                    float t3 = fmaxf(bf2f(r[3]) * sc0.w + sh0.w, 0.f);
                    float t4 = fmaxf(bf2f(r[4]) * sc1.x + sh1.x, 0.f);
                    float t5 = fmaxf(bf2f(r[5]) * sc1.y + sh1.y, 0.f);
                    float t6 = fmaxf(bf2f(r[6]) * sc1.z + sh1.z, 0.f);
                    float t7 = fmaxf(bf2f(r[7]) * sc1.w + sh1.w, 0.f);
                    v[0] = f2bf(t0); v[1] = f2bf(t1); v[2] = f2bf(t2); v[3] = f2bf(t3);
                    v[4] = f2bf(t4); v[5] = f2bf(t5); v[6] = f2bf(t6); v[7] = f2bf(t7);
                } else {
                    v = *(const ushort8v*)(Ab + (size_t)grow * K + kc);
                }
            }
            *(ushort8v*)(Asb + e * 8) = v;
        }
        // stage B tile [BN_][32] bf16 from Bt[N,K]
#pragma unroll
        for (int i = 0; i < BN_ / 64; ++i) {
            int e = tid + i * 256;
            int n = e >> 2, c = e & 3;
            ushort8v v = *(const ushort8v*)(Bt + (size_t)(col_base + n) * K + kt + c * 8);
            *(ushort8v*)(Bsb + e * 8) = v;
        }
        __syncthreads();
        bf16x8 af[4], bfr[NREP];
#pragma unroll
        for (int m = 0; m < 4; ++m)
            af[m] = *(const bf16x8*)(Asb + (wrow * 64 + m * 16 + (lane & 15)) * 32 + (lane >> 4) * 8);
#pragma unroll
        for (int n = 0; n < NREP; ++n)
            bfr[n] = *(const bf16x8*)(Bsb + (wcol * (BN_ / 2) + n * 16 + (lane & 15)) * 32 + (lane >> 4) * 8);
#pragma unroll
        for (int m = 0; m < 4; ++m)
#pragma unroll
            for (int n = 0; n < NREP; ++n)
                acc[m][n] = __builtin_amdgcn_mfma_f32_16x16x32_bf16(af[m], bfr[n], acc[m][n], 0, 0, 0);
    }
    // epilogue: C/D mapping col=lane&15, row=(lane>>4)*4+j
    const int lc = lane & 15;
    const int lr = (lane >> 4) * 4;
#pragma unroll
    for (int m = 0; m < 4; ++m) {
        int gr0 = row_base + wrow * 64 + m * 16 + lr;
#pragma unroll
        for (int n = 0; n < NREP; ++n) {
            int gc = col_base + wcol * (BN_ / 2) + n * 16 + lc;
            float bb = bias[gc];
#pragma unroll
            for (int j = 0; j < 4; ++j) {
                int gr = gr0 + j;
                if (gr < M) Cb[(size_t)gr * Nd + gc] = f2bf(acc[m][n][j] + bb);
            }
        }
    }
    if (STATS) {
#pragma unroll
        for (int n = 0; n < NREP; ++n) {
            int gc = col_base + wcol * (BN_ / 2) + n * 16 + lc;
            float bb = bias[gc];
            float s = 0.f, s2 = 0.f;
#pragma unroll
            for (int m = 0; m < 4; ++m) {
                int gr0 = row_base + wrow * 64 + m * 16 + lr;
#pragma unroll
                for (int j = 0; j < 4; ++j) {
                    if (gr0 + j < M) {
                        float v = acc[m][n][j] + bb;
                        s += v;
                        s2 += v * v;
                    }
                }
            }
            s += __shfl_xor(s, 16); s += __shfl_xor(s, 32);
            s2 += __shfl_xor(s2, 16); s2 += __shfl_xor(s2, 32);
            if ((lane >> 4) == 0) {
                atomicAdd(&sum[gc], s);
                atomicAdd(&sumsq[gc], s2);
            }
        }
    }
}

__global__ void k_bnfin(const float* __restrict__ sum, const float* __restrict__ sq,
                        const float* __restrict__ g, const float* __restrict__ be,
                        float* scale, float* shift) {
    int c = threadIdx.x;
    float mu = sum[c] * (1.f / NN);
    float var = sq[c] * (1.f / NN) - mu * mu;
    float sc = g[c] * rsqrtf(var + BN_EPS);
    scale[c] = sc;
    shift[c] = be[c] - mu * sc;
}

// ---------------- propagation ----------------
__device__ inline float wred_sum(float v) {
#pragma unroll
    for (int m = 32; m >= 1; m >>= 1) v += __shfl_xor(v, m);
    return v;
}
__device__ inline float wred_max(float v) {
#pragma unroll
    for (int m = 32; m >= 1; m >>= 1) v = fmaxf(v, __shfl_xor(v, m));
    return v;
}

__global__ void k_hop(const unsigned short* __restrict__ xin,
                      unsigned short* __restrict__ xout,
                      const int* __restrict__ offs, const int* __restrict__ csrc,
                      const float* __restrict__ cw, const float* __restrict__ dis,
                      int n) {
    int wid = (int)((blockIdx.x * (size_t)blockDim.x + threadIdx.x) >> 6);
    int lane = threadIdx.x & 63;
    if (wid >= n) return;
    float dn = dis[wid];
    float y = dn * dn * bf2f(xin[(size_t)wid * CC + lane]);
    int p0 = offs[wid], p1 = offs[wid + 1];
    int p = p0;
    for (; p + 4 <= p1; p += 4) {
        int s0 = csrc[p + 0], s1 = csrc[p + 1], s2 = csrc[p + 2], s3 = csrc[p + 3];
        float w0 = cw[p + 0], w1 = cw[p + 1], w2 = cw[p + 2], w3 = cw[p + 3];
        float a0 = bf2f(xin[(size_t)s0 * CC + lane]);
        float a1 = bf2f(xin[(size_t)s1 * CC + lane]);
        float a2 = bf2f(xin[(size_t)s2 * CC + lane]);
        float a3 = bf2f(xin[(size_t)s3 * CC + lane]);
        y += w0 * a0;
        y += w1 * a1;
        y += w2 * a2;
        y += w3 * a3;
    }
    for (; p < p1; p++)
        y += cw[p] * bf2f(xin[(size_t)csrc[p] * CC + lane]);
    xout[(size_t)wid * CC + lane] = f2bf(y);
}

struct XPack { const unsigned short* p[KHOPS + 1]; };

__global__ void k_finprop(XPack xp, const float* __restrict__ pw,
                          const float* __restrict__ pbp, float* __restrict__ out, int n) {
    int wid = (int)((blockIdx.x * (size_t)blockDim.x + threadIdx.x) >> 6);
    int lane = threadIdx.x & 63;
    if (wid >= n) return;
    float pwl = pw[lane];
    float pb0 = pbp[0];
    float v[KHOPS + 1];
#pragma unroll
    for (int k = 0; k <= KHOPS; k++)
        v[k] = bf2f(xp.p[k][(size_t)wid * CC + lane]);
    float o = 0.f;
#pragma unroll
    for (int k = 0; k <= KHOPS; k++) {
        float d = wred_sum(v[k] * pwl);
        float s = 1.f / (1.f + expf(-(d + pb0)));
        o += s * v[k];
    }
    float m = wred_max(o);
    float e = expf(o - m);
    float su = wred_sum(e);
    out[(size_t)wid * CC + lane] = o - m - logf(su);
}

// ---------------- launch ----------------
extern "C" void kernel_launch(void* const* d_in, const int* in_sizes, int n_in,
                              void* d_out, int out_size, void* d_ws, size_t ws_size,
                              hipStream_t stream) {
    const float* x  = (const float*)d_in[0];
    const float* W0 = (const float*)d_in[1];
    const float* b0 = (const float*)d_in[2];
    const float* g0 = (const float*)d_in[3];
    const float* be0 = (const float*)d_in[4];
    const float* W1 = (const float*)d_in[5];
    const float* b1 = (const float*)d_in[6];
    const float* g1 = (const float*)d_in[7];
    const float* be1 = (const float*)d_in[8];
    const float* W2 = (const float*)d_in[9];
    const float* b2 = (const float*)d_in[10];
    const float* pw = (const float*)d_in[11];
    const float* pb = (const float*)d_in[12];
    const int* ei = (const int*)d_in[13];
    const int E = in_sizes[13] / 2;
    const int* esrc = ei;
    const int* edst = ei + E;

    char* ws = (char*)d_ws;
    const size_t XKB = (size_t)NN * CC * 2;  // 12,800,000 B per hop buffer
    unsigned short* h0b = (unsigned short*)(ws + 0);          // [N,256] bf16 (pre-BN)
    unsigned short* h1b = (unsigned short*)(ws + 51200000);   // [N,256] bf16 (pre-BN)
    // hop buffers xk[0..10] (bf16 [N,64]), aliased over h0b/h1b after death:
    unsigned short* xk[KHOPS + 1];
    xk[0] = (unsigned short*)(ws + 0);                         // over h0b (dead after gemm1)
    xk[5] = (unsigned short*)(ws + XKB);
    xk[6] = (unsigned short*)(ws + 2 * XKB);
    xk[7] = (unsigned short*)(ws + 3 * XKB);
    xk[1] = (unsigned short*)(ws + 51200000);                  // over h1b (dead after gemm2)
    xk[2] = (unsigned short*)(ws + 51200000 + XKB);
    xk[3] = (unsigned short*)(ws + 51200000 + 2 * XKB);
    xk[4] = (unsigned short*)(ws + 51200000 + 3 * XKB);
    xk[8] = (unsigned short*)(ws + 102400000);
    xk[9] = (unsigned short*)(ws + 115200000);
    xk[10] = (unsigned short*)(ws + 128000000);

    int*   deg  = (int*)  (ws + 140800000);
    float* dis  = (float*)(ws + 141200000);
    int*   offs = (int*)  (ws + 141600000);   // NN+1 ints
    int*   cur  = (int*)  (ws + 142000064);
    int*   csrc = (int*)  (ws + 142400064);
    float* cw   = (float*)(ws + 148800064);
    float* stats = (float*)(ws + 155200064);  // 2048 f32
    int*   part = (int*)  (ws + 155208256);   // scan partials
    unsigned short* W0t = (unsigned short*)(ws + 155209280);  // [256,512]
    unsigned short* W1t = (unsigned short*)(ws + 155471424);  // [256,256]
    unsigned short* W2t = (unsigned short*)(ws + 155602496);  // [64,256]

    float* sum0 = stats,        *sq0 = stats + 256;
    float* sum1 = stats + 512,  *sq1 = stats + 768;
    float* scale0 = stats + 1024, *shift0 = stats + 1280;
    float* scale1 = stats + 1536, *shift1 = stats + 1792;

    float* out = (float*)d_out;

    const int TPB = 256;
    int ngrid = (NN + TPB - 1) / TPB;
    int egrid = (E + TPB - 1) / TPB;
    int wgrid = (NN * 64 + TPB - 1) / TPB;  // one wave per node
    int mtiles = (NN + 127) / 128;          // 782

    // graph preprocessing
    k_zero<<<2, 1024, 0, stream>>>(stats, 2048);
    k_deg_init<<<ngrid, TPB, 0, stream>>>(deg, NN);
    k_deg_count<<<egrid, TPB, 0, stream>>>(edst, E, deg);
    k_dis<<<ngrid, TPB, 0, stream>>>(deg, dis, NN);
    k_scan1<<<SCAN_NB, SCAN_B, 0, stream>>>(deg, part, NN);
    k_scan2<<<1, 64, 0, stream>>>(part, offs + NN, SCAN_NB);
    k_scan3<<<SCAN_NB, SCAN_B, 0, stream>>>(deg, part, offs, cur, NN);
    k_fill<<<egrid, TPB, 0, stream>>>(esrc, edst, E, dis, cur, csrc, cw);

    // weight transpose+cast (tiny)
    k_wt<<<(FF * HH + TPB - 1) / TPB, TPB, 0, stream>>>(W0, W0t, FF, HH);
    k_wt<<<(HH * HH + TPB - 1) / TPB, TPB, 0, stream>>>(W1, W1t, HH, HH);
    k_wt<<<(HH * CC + TPB - 1) / TPB, TPB, 0, stream>>>(W2, W2t, HH, CC);

    // layer 0: x(f32) @ W0 -> h0b (pre-BN bf16) + stats0
    k_gemm_mfma<1, 128, 0, 1><<<dim3(HH / 128, mtiles), 256, 0, stream>>>(
        x, W0t, b0, h0b, nullptr, nullptr, sum0, sq0, NN, FF, HH);
    k_bnfin<<<1, 256, 0, stream>>>(sum0, sq0, g0, be0, scale0, shift0);

    // layer 1: BN0+ReLU(h0b) @ W1 -> h1b (pre-BN bf16) + stats1
    k_gemm_mfma<0, 128, 1, 1><<<dim3(HH / 128, mtiles), 256, 0, stream>>>(
        h0b, W1t, b1, h1b, scale0, shift0, sum1, sq1, NN, HH, HH);
    k_bnfin<<<1, 256, 0, stream>>>(sum1, sq1, g1, be1, scale1, shift1);

    // layer 2: BN1+ReLU(h1b) @ W2 -> xk0 (bf16 logits)
    k_gemm_mfma<0, 64, 1, 0><<<dim3(1, mtiles), 256, 0, stream>>>(
        h1b, W2t, b2, xk[0], scale1, shift1, nullptr, nullptr, NN, HH, CC);

    // propagation: xk[k+1] = Ahat xk[k]
    for (int k = 0; k < KHOPS; k++)
        k_hop<<<wgrid, TPB, 0, stream>>>(xk[k], xk[k + 1], offs, csrc, cw, dis, NN);

    // fused score + weighted-sum + log-softmax
    XPack xp;
    for (int k = 0; k <= KHOPS; k++) xp.p[k] = xk[k];
    k_finprop<<<wgrid, TPB, 0, stream>>>(xp, pw, pb, out, NN);
}

// Round 4
// 1085.746 us; speedup vs baseline: 2.7603x; 1.0833x over previous
//
#include <hip/hip_runtime.h>
#include <hip/hip_bf16.h>
#include <math.h>

// Problem constants (from reference)
#define NN 100000
#define FF 512
#define HH 256
#define CC 64
#define KHOPS 10
#define BN_EPS 1e-5f

typedef __bf16 bf16x8 __attribute__((ext_vector_type(8)));
typedef float f32x4 __attribute__((ext_vector_type(4)));
typedef unsigned short ushort8v __attribute__((ext_vector_type(8)));

__device__ __forceinline__ unsigned short f2bf(float f) {
    __bf16 b = (__bf16)f;  // v_cvt RNE
    return __builtin_bit_cast(unsigned short, b);
}
__device__ __forceinline__ float bf2f(unsigned short h) {
    unsigned u = ((unsigned)h) << 16;
    return __builtin_bit_cast(float, u);
}

// ---------------- utility kernels ----------------
__global__ void k_zero(float* p, int n) {
    int i = blockIdx.x * blockDim.x + threadIdx.x;
    if (i < n) p[i] = 0.f;
}

__global__ void k_deg_init(int* deg, int n) {
    int i = blockIdx.x * blockDim.x + threadIdx.x;
    if (i < n) deg[i] = 1;  // self-loop
}

__global__ void k_deg_count(const int* __restrict__ dst, int e, int* deg) {
    for (int i = blockIdx.x * blockDim.x + threadIdx.x; i < e; i += gridDim.x * blockDim.x)
        atomicAdd(&deg[dst[i]], 1);
}

__global__ void k_dis(const int* __restrict__ deg, float* dis, int n) {
    int i = blockIdx.x * blockDim.x + threadIdx.x;
    if (i < n) dis[i] = rsqrtf((float)deg[i]);
}

// ---------------- hierarchical scan: offs = exclusive prefix of (deg-1) ----------------
#define SCAN_B 1024
#define SCAN_NB ((NN + SCAN_B - 1) / SCAN_B)  // 98

__global__ void k_scan1(const int* __restrict__ deg, int* __restrict__ part, int n) {
    __shared__ int ls[SCAN_B];
    int i = blockIdx.x * SCAN_B + threadIdx.x;
    ls[threadIdx.x] = (i < n) ? deg[i] - 1 : 0;
    __syncthreads();
    for (int d = SCAN_B / 2; d > 0; d >>= 1) {
        if (threadIdx.x < d) ls[threadIdx.x] += ls[threadIdx.x + d];
        __syncthreads();
    }
    if (threadIdx.x == 0) part[blockIdx.x] = ls[0];
}

__global__ void k_scan2(int* part, int* offs_last, int nb) {
    if (threadIdx.x == 0) {
        int run = 0;
        for (int b = 0; b < nb; b++) { int v = part[b]; part[b] = run; run += v; }
        offs_last[0] = run;  // == E
    }
}

__global__ void k_scan3(const int* __restrict__ deg, const int* __restrict__ part,
                        int* __restrict__ offs, int* __restrict__ cur, int n) {
    __shared__ int ls[SCAN_B];
    int i = blockIdx.x * SCAN_B + threadIdx.x;
    int v = (i < n) ? deg[i] - 1 : 0;
    ls[threadIdx.x] = v;
    __syncthreads();
    for (int d = 1; d < SCAN_B; d <<= 1) {
        int t = (threadIdx.x >= d) ? ls[threadIdx.x - d] : 0;
        __syncthreads();
        ls[threadIdx.x] += t;
        __syncthreads();
    }
    if (i < n) {
        int ex = part[blockIdx.x] + ls[threadIdx.x] - v;
        offs[i] = ex;
        cur[i] = ex;
    }
}

__global__ void k_fill(const int* __restrict__ src, const int* __restrict__ dst, int e,
                       const float* __restrict__ dis, int* cursor,
                       int* __restrict__ csrc, float* __restrict__ cw) {
    for (int i = blockIdx.x * blockDim.x + threadIdx.x; i < e; i += gridDim.x * blockDim.x) {
        int d = dst[i];
        int s = src[i];
        int p = atomicAdd(&cursor[d], 1);
        csrc[p] = s;
        cw[p] = dis[s] * dis[d];
    }
}

// transpose+cast weights: Wt[n*K+k] = bf16(W[k*N+n])
__global__ void k_wt(const float* __restrict__ W, unsigned short* __restrict__ Wt,
                     int K, int N) {
    int i = blockIdx.x * blockDim.x + threadIdx.x;
    if (i < K * N) {
        int n = i / K;
        int k = i - n * K;
        Wt[i] = f2bf(W[(size_t)k * N + n]);
    }
}

// ---------------- bf16 MFMA GEMM, 2-phase reg-prefetch pipeline ----------------
// C[M,Nd](bf16) = act(A) @ Bt^T + bias.  BM=128, BK=32, 4 waves (2x2).
// Double-buffered LDS; next tile's global loads issued into regs BEFORE the
// current tile's MFMA, committed to the other LDS buffer after (vmcnt wait
// lands post-MFMA). One barrier per K-step.
template <int AF32, int BN_, int FUSEBN, int STATS>
__global__ __launch_bounds__(256) void k_gemm_mfma(
    const void* __restrict__ Av, const unsigned short* __restrict__ Bt,
    const float* __restrict__ bias, unsigned short* __restrict__ Cb,
    const float* __restrict__ bnscale, const float* __restrict__ bnshift,
    float* __restrict__ sum, float* __restrict__ sumsq,
    int M, int K, int Nd) {
    constexpr int NREP = BN_ / 32;
    constexpr int BSTEP = BN_ / 64;
    __shared__ unsigned short Asb[2][128 * 32];
    __shared__ unsigned short Bsb[2][BN_ * 32];
    const int tid = threadIdx.x;
    const int lane = tid & 63;
    const int wid = tid >> 6;
    const int wrow = wid >> 1, wcol = wid & 1;
    const int row_base = blockIdx.y * 128;
    const int col_base = blockIdx.x * BN_;

    const float* Af = (const float*)Av;
    const unsigned short* Ab = (const unsigned short*)Av;

    f32x4 acc[4][NREP];
#pragma unroll
    for (int m = 0; m < 4; m++)
#pragma unroll
        for (int n = 0; n < NREP; n++)
#pragma unroll
            for (int j = 0; j < 4; j++) acc[m][n][j] = 0.f;

    // staging registers
    float4 aF[4];
    ushort8v aB[2];
    float4 scv0, scv1, shv0, shv1;
    ushort8v bR[BSTEP];

    auto issue_loads = [&](int kt) {
#pragma unroll
        for (int i = 0; i < 2; ++i) {
            int e = tid + i * 256;
            int row = e >> 2;
            int grow = row_base + row;
            int kc = kt + (e & 3) * 8;
            if (AF32) {
                if (grow < M) {
                    const float* p = Af + (size_t)grow * K + kc;
                    aF[2 * i] = *(const float4*)p;
                    aF[2 * i + 1] = *(const float4*)(p + 4);
                } else {
                    aF[2 * i] = make_float4(0.f, 0.f, 0.f, 0.f);
                    aF[2 * i + 1] = make_float4(0.f, 0.f, 0.f, 0.f);
                }
            } else {
                ushort8v z = {0, 0, 0, 0, 0, 0, 0, 0};
                aB[i] = (grow < M) ? *(const ushort8v*)(Ab + (size_t)grow * K + kc) : z;
            }
        }
        if (FUSEBN) {
            int kc = kt + (tid & 3) * 8;  // same for both i (256 % 4 == 0)
            scv0 = *(const float4*)(bnscale + kc);
            scv1 = *(const float4*)(bnscale + kc + 4);
            shv0 = *(const float4*)(bnshift + kc);
            shv1 = *(const float4*)(bnshift + kc + 4);
        }
#pragma unroll
        for (int i = 0; i < BSTEP; ++i) {
            int e = tid + i * 256;
            int nn = e >> 2, c = e & 3;
            bR[i] = *(const ushort8v*)(Bt + (size_t)(col_base + nn) * K + kt + c * 8);
        }
    };

    auto commit = [&](int buf) {
#pragma unroll
        for (int i = 0; i < 2; ++i) {
            int e = tid + i * 256;
            ushort8v v;
            if (AF32) {
                float4 f0 = aF[2 * i], f1 = aF[2 * i + 1];
                v[0] = f2bf(f0.x); v[1] = f2bf(f0.y); v[2] = f2bf(f0.z); v[3] = f2bf(f0.w);
                v[4] = f2bf(f1.x); v[5] = f2bf(f1.y); v[6] = f2bf(f1.z); v[7] = f2bf(f1.w);
            } else if (FUSEBN) {
                ushort8v r = aB[i];
                v[0] = f2bf(fmaxf(bf2f(r[0]) * scv0.x + shv0.x, 0.f));
                v[1] = f2bf(fmaxf(bf2f(r[1]) * scv0.y + shv0.y, 0.f));
                v[2] = f2bf(fmaxf(bf2f(r[2]) * scv0.z + shv0.z, 0.f));
                v[3] = f2bf(fmaxf(bf2f(r[3]) * scv0.w + shv0.w, 0.f));
                v[4] = f2bf(fmaxf(bf2f(r[4]) * scv1.x + shv1.x, 0.f));
                v[5] = f2bf(fmaxf(bf2f(r[5]) * scv1.y + shv1.y, 0.f));
                v[6] = f2bf(fmaxf(bf2f(r[6]) * scv1.z + shv1.z, 0.f));
                v[7] = f2bf(fmaxf(bf2f(r[7]) * scv1.w + shv1.w, 0.f));
            } else {
                v = aB[i];
            }
            *(ushort8v*)(Asb[buf] + e * 8) = v;
        }
#pragma unroll
        for (int i = 0; i < BSTEP; ++i) {
            int e = tid + i * 256;
            *(ushort8v*)(Bsb[buf] + e * 8) = bR[i];
        }
    };

    const int nt = K / 32;
    issue_loads(0);
    commit(0);
    __syncthreads();

    for (int t = 0; t < nt; ++t) {
        int cur = t & 1;
        if (t + 1 < nt) issue_loads((t + 1) * 32);  // in-flight during MFMA
        bf16x8 af[4], bfr[NREP];
#pragma unroll
        for (int m = 0; m < 4; ++m)
            af[m] = *(const bf16x8*)(Asb[cur] + (wrow * 64 + m * 16 + (lane & 15)) * 32 + (lane >> 4) * 8);
#pragma unroll
        for (int n = 0; n < NREP; ++n)
            bfr[n] = *(const bf16x8*)(Bsb[cur] + (wcol * (BN_ / 2) + n * 16 + (lane & 15)) * 32 + (lane >> 4) * 8);
#pragma unroll
        for (int m = 0; m < 4; ++m)
#pragma unroll
            for (int n = 0; n < NREP; ++n)
                acc[m][n] = __builtin_amdgcn_mfma_f32_16x16x32_bf16(af[m], bfr[n], acc[m][n], 0, 0, 0);
        if (t + 1 < nt) commit(1 - cur);  // vmcnt wait sits here, after MFMA issue
        __syncthreads();
    }

    // epilogue: C/D mapping col=lane&15, row=(lane>>4)*4+j
    const int lc = lane & 15;
    const int lr = (lane >> 4) * 4;
#pragma unroll
    for (int m = 0; m < 4; ++m) {
        int gr0 = row_base + wrow * 64 + m * 16 + lr;
#pragma unroll
        for (int n = 0; n < NREP; ++n) {
            int gc = col_base + wcol * (BN_ / 2) + n * 16 + lc;
            float bb = bias[gc];
#pragma unroll
            for (int j = 0; j < 4; ++j) {
                int gr = gr0 + j;
                if (gr < M) Cb[(size_t)gr * Nd + gc] = f2bf(acc[m][n][j] + bb);
            }
        }
    }
    if (STATS) {
#pragma unroll
        for (int n = 0; n < NREP; ++n) {
            int gc = col_base + wcol * (BN_ / 2) + n * 16 + lc;
            float bb = bias[gc];
            float s = 0.f, s2 = 0.f;
#pragma unroll
            for (int m = 0; m < 4; ++m) {
                int gr0 = row_base + wrow * 64 + m * 16 + lr;
#pragma unroll
                for (int j = 0; j < 4; ++j) {
                    if (gr0 + j < M) {
                        float v = acc[m][n][j] + bb;
                        s += v;
                        s2 += v * v;
                    }
                }
            }
            s += __shfl_xor(s, 16); s += __shfl_xor(s, 32);
            s2 += __shfl_xor(s2, 16); s2 += __shfl_xor(s2, 32);
            if ((lane >> 4) == 0) {
                atomicAdd(&sum[gc], s);
                atomicAdd(&sumsq[gc], s2);
            }
        }
    }
}

__global__ void k_bnfin(const float* __restrict__ sum, const float* __restrict__ sq,
                        const float* __restrict__ g, const float* __restrict__ be,
                        float* scale, float* shift) {
    int c = threadIdx.x;
    float mu = sum[c] * (1.f / NN);
    float var = sq[c] * (1.f / NN) - mu * mu;
    float sc = g[c] * rsqrtf(var + BN_EPS);
    scale[c] = sc;
    shift[c] = be[c] - mu * sc;
}

// ---------------- propagation ----------------
// one wave per node; two 32-lane halves process even/odd neighbors with
// uint (2-channel) loads; combined via shfl_xor(32).
__global__ void k_hop(const unsigned short* __restrict__ xin,
                      unsigned short* __restrict__ xout,
                      const int* __restrict__ offs, const int* __restrict__ csrc,
                      const float* __restrict__ cw, const float* __restrict__ dis,
                      int n) {
    int wid = (int)((blockIdx.x * (size_t)blockDim.x + threadIdx.x) >> 6);
    if (wid >= n) return;
    int lane = threadIdx.x & 63;
    int hf = lane >> 5;
    int l = lane & 31;
    const unsigned* x32 = (const unsigned*)xin;
    unsigned* o32 = (unsigned*)xout;
    float y0 = 0.f, y1 = 0.f;
    if (hf == 0) {
        float dn = dis[wid];
        float w = dn * dn;
        unsigned sv = x32[(size_t)wid * 32 + l];
        y0 = w * bf2f((unsigned short)(sv & 0xFFFF));
        y1 = w * bf2f((unsigned short)(sv >> 16));
    }
    int p0 = offs[wid], p1 = offs[wid + 1];
    int p = p0 + hf;
    for (; p + 2 < p1; p += 4) {
        int sA = csrc[p], sB = csrc[p + 2];
        float wA = cw[p], wB = cw[p + 2];
        unsigned vA = x32[(size_t)sA * 32 + l];
        unsigned vB = x32[(size_t)sB * 32 + l];
        y0 += wA * bf2f((unsigned short)(vA & 0xFFFF));
        y1 += wA * bf2f((unsigned short)(vA >> 16));
        y0 += wB * bf2f((unsigned short)(vB & 0xFFFF));
        y1 += wB * bf2f((unsigned short)(vB >> 16));
    }
    for (; p < p1; p += 2) {
        int s = csrc[p];
        float w = cw[p];
        unsigned v = x32[(size_t)s * 32 + l];
        y0 += w * bf2f((unsigned short)(v & 0xFFFF));
        y1 += w * bf2f((unsigned short)(v >> 16));
    }
    y0 += __shfl_xor(y0, 32);
    y1 += __shfl_xor(y1, 32);
    if (hf == 0)
        o32[(size_t)wid * 32 + l] = ((unsigned)f2bf(y1) << 16) | (unsigned)f2bf(y0);
}

struct XPack { const unsigned short* p[KHOPS + 1]; };

// two nodes per wave (one per 32-lane half), uint loads, 32-lane reductions
__global__ void k_finprop(XPack xp, const float* __restrict__ pw,
                          const float* __restrict__ pbp, float* __restrict__ out, int n) {
    int gw = (int)((blockIdx.x * (size_t)blockDim.x + threadIdx.x) >> 6);
    int lane = threadIdx.x & 63;
    int hf = lane >> 5;
    int l = lane & 31;
    int node = gw * 2 + hf;
    if (node >= n) return;
    float pw0 = pw[2 * l], pw1 = pw[2 * l + 1];
    float pb0 = pbp[0];
    float o0 = 0.f, o1 = 0.f;
#pragma unroll
    for (int k = 0; k <= KHOPS; k++) {
        unsigned v = ((const unsigned*)xp.p[k])[(size_t)node * 32 + l];
        float v0 = bf2f((unsigned short)(v & 0xFFFF));
        float v1 = bf2f((unsigned short)(v >> 16));
        float d = v0 * pw0 + v1 * pw1;
#pragma unroll
        for (int m = 16; m >= 1; m >>= 1) d += __shfl_xor(d, m);
        float s = 1.f / (1.f + expf(-(d + pb0)));
        o0 += s * v0;
        o1 += s * v1;
    }
    float mx = fmaxf(o0, o1);
#pragma unroll
    for (int m = 16; m >= 1; m >>= 1) mx = fmaxf(mx, __shfl_xor(mx, m));
    float e = expf(o0 - mx) + expf(o1 - mx);
#pragma unroll
    for (int m = 16; m >= 1; m >>= 1) e += __shfl_xor(e, m);
    float lg = mx + logf(e);
    float2 r = make_float2(o0 - lg, o1 - lg);
    *(float2*)(out + (size_t)node * 64 + 2 * l) = r;
}

// ---------------- launch ----------------
extern "C" void kernel_launch(void* const* d_in, const int* in_sizes, int n_in,
                              void* d_out, int out_size, void* d_ws, size_t ws_size,
                              hipStream_t stream) {
    const float* x  = (const float*)d_in[0];
    const float* W0 = (const float*)d_in[1];
    const float* b0 = (const float*)d_in[2];
    const float* g0 = (const float*)d_in[3];
    const float* be0 = (const float*)d_in[4];
    const float* W1 = (const float*)d_in[5];
    const float* b1 = (const float*)d_in[6];
    const float* g1 = (const float*)d_in[7];
    const float* be1 = (const float*)d_in[8];
    const float* W2 = (const float*)d_in[9];
    const float* b2 = (const float*)d_in[10];
    const float* pw = (const float*)d_in[11];
    const float* pb = (const float*)d_in[12];
    const int* ei = (const int*)d_in[13];
    const int E = in_sizes[13] / 2;
    const int* esrc = ei;
    const int* edst = ei + E;

    char* ws = (char*)d_ws;
    const size_t XKB = (size_t)NN * CC * 2;  // 12,800,000 B per hop buffer
    unsigned short* h0b = (unsigned short*)(ws + 0);          // [N,256] bf16 (pre-BN)
    unsigned short* h1b = (unsigned short*)(ws + 51200000);   // [N,256] bf16 (pre-BN)
    unsigned short* xk[KHOPS + 1];
    xk[0] = (unsigned short*)(ws + 0);                         // over h0b (dead after gemm1)
    xk[5] = (unsigned short*)(ws + XKB);
    xk[6] = (unsigned short*)(ws + 2 * XKB);
    xk[7] = (unsigned short*)(ws + 3 * XKB);
    xk[1] = (unsigned short*)(ws + 51200000);                  // over h1b (dead after gemm2)
    xk[2] = (unsigned short*)(ws + 51200000 + XKB);
    xk[3] = (unsigned short*)(ws + 51200000 + 2 * XKB);
    xk[4] = (unsigned short*)(ws + 51200000 + 3 * XKB);
    xk[8] = (unsigned short*)(ws + 102400000);
    xk[9] = (unsigned short*)(ws + 115200000);
    xk[10] = (unsigned short*)(ws + 128000000);

    int*   deg  = (int*)  (ws + 140800000);
    float* dis  = (float*)(ws + 141200000);
    int*   offs = (int*)  (ws + 141600000);   // NN+1 ints
    int*   cur  = (int*)  (ws + 142000064);
    int*   csrc = (int*)  (ws + 142400064);
    float* cw   = (float*)(ws + 148800064);
    float* stats = (float*)(ws + 155200064);  // 2048 f32
    int*   part = (int*)  (ws + 155208256);   // scan partials
    unsigned short* W0t = (unsigned short*)(ws + 155209280);  // [256,512]
    unsigned short* W1t = (unsigned short*)(ws + 155471424);  // [256,256]
    unsigned short* W2t = (unsigned short*)(ws + 155602496);  // [64,256]

    float* sum0 = stats,        *sq0 = stats + 256;
    float* sum1 = stats + 512,  *sq1 = stats + 768;
    float* scale0 = stats + 1024, *shift0 = stats + 1280;
    float* scale1 = stats + 1536, *shift1 = stats + 1792;

    float* out = (float*)d_out;

    const int TPB = 256;
    int ngrid = (NN + TPB - 1) / TPB;
    int egrid = (E + TPB - 1) / TPB;
    int wgrid = (NN * 64 + TPB - 1) / TPB;       // one wave per node
    int wgrid2 = (((NN + 1) / 2) * 64 + TPB - 1) / TPB;  // two nodes per wave
    int mtiles = (NN + 127) / 128;               // 782

    // graph preprocessing
    k_zero<<<2, 1024, 0, stream>>>(stats, 2048);
    k_deg_init<<<ngrid, TPB, 0, stream>>>(deg, NN);
    k_deg_count<<<egrid, TPB, 0, stream>>>(edst, E, deg);
    k_dis<<<ngrid, TPB, 0, stream>>>(deg, dis, NN);
    k_scan1<<<SCAN_NB, SCAN_B, 0, stream>>>(deg, part, NN);
    k_scan2<<<1, 64, 0, stream>>>(part, offs + NN, SCAN_NB);
    k_scan3<<<SCAN_NB, SCAN_B, 0, stream>>>(deg, part, offs, cur, NN);
    k_fill<<<egrid, TPB, 0, stream>>>(esrc, edst, E, dis, cur, csrc, cw);

    // weight transpose+cast (tiny)
    k_wt<<<(FF * HH + TPB - 1) / TPB, TPB, 0, stream>>>(W0, W0t, FF, HH);
    k_wt<<<(HH * HH + TPB - 1) / TPB, TPB, 0, stream>>>(W1, W1t, HH, HH);
    k_wt<<<(HH * CC + TPB - 1) / TPB, TPB, 0, stream>>>(W2, W2t, HH, CC);

    // layer 0: x(f32) @ W0 -> h0b (pre-BN bf16) + stats0
    k_gemm_mfma<1, 128, 0, 1><<<dim3(HH / 128, mtiles), 256, 0, stream>>>(
        x, W0t, b0, h0b, nullptr, nullptr, sum0, sq0, NN, FF, HH);
    k_bnfin<<<1, 256, 0, stream>>>(sum0, sq0, g0, be0, scale0, shift0);

    // layer 1: BN0+ReLU(h0b) @ W1 -> h1b (pre-BN bf16) + stats1
    k_gemm_mfma<0, 128, 1, 1><<<dim3(HH / 128, mtiles), 256, 0, stream>>>(
        h0b, W1t, b1, h1b, scale0, shift0, sum1, sq1, NN, HH, HH);
    k_bnfin<<<1, 256, 0, stream>>>(sum1, sq1, g1, be1, scale1, shift1);

    // layer 2: BN1+ReLU(h1b) @ W2 -> xk0 (bf16 logits)
    k_gemm_mfma<0, 64, 1, 0><<<dim3(1, mtiles), 256, 0, stream>>>(
        h1b, W2t, b2, xk[0], scale1, shift1, nullptr, nullptr, NN, HH, CC);

    // propagation: xk[k+1] = Ahat xk[k]
    for (int k = 0; k < KHOPS; k++)
        k_hop<<<wgrid, TPB, 0, stream>>>(xk[k], xk[k + 1], offs, csrc, cw, dis, NN);

    // fused score + weighted-sum + log-softmax
    XPack xp;
    for (int k = 0; k <= KHOPS; k++) xp.p[k] = xk[k];
    k_finprop<<<wgrid2, TPB, 0, stream>>>(xp, pw, pb, out, NN);
}

// Round 5
// 954.425 us; speedup vs baseline: 3.1401x; 1.1376x over previous
//
#include <hip/hip_runtime.h>
#include <hip/hip_bf16.h>
#include <math.h>

// Problem constants (from reference)
#define NN 100000
#define FF 512
#define HH 256
#define CC 64
#define KHOPS 10
#define BN_EPS 1e-5f

typedef __bf16 bf16x8 __attribute__((ext_vector_type(8)));
typedef float f32x4 __attribute__((ext_vector_type(4)));
typedef unsigned short ushort8v __attribute__((ext_vector_type(8)));

__device__ __forceinline__ unsigned short f2bf(float f) {
    __bf16 b = (__bf16)f;  // v_cvt RNE
    return __builtin_bit_cast(unsigned short, b);
}
__device__ __forceinline__ float bf2f(unsigned short h) {
    unsigned u = ((unsigned)h) << 16;
    return __builtin_bit_cast(float, u);
}

// async global->LDS, 16B per lane. LDS dest is wave-uniform base + lane*16
// (we pass per-lane ptrs that already have that shape).
typedef __attribute__((address_space(1))) const void g_void;
typedef __attribute__((address_space(3))) void l_void;
__device__ __forceinline__ void gl2lds16(const void* g, void* l) {
    __builtin_amdgcn_global_load_lds((g_void*)g, (l_void*)l, 16, 0, 0);
}

// ---------------- utility kernels ----------------
__global__ void k_zero(float* p, int n) {
    int i = blockIdx.x * blockDim.x + threadIdx.x;
    if (i < n) p[i] = 0.f;
}

__global__ void k_deg_init(int* deg, int n) {
    int i = blockIdx.x * blockDim.x + threadIdx.x;
    if (i < n) deg[i] = 1;  // self-loop
}

__global__ void k_deg_count(const int* __restrict__ dst, int e, int* deg) {
    for (int i = blockIdx.x * blockDim.x + threadIdx.x; i < e; i += gridDim.x * blockDim.x)
        atomicAdd(&deg[dst[i]], 1);
}

__global__ void k_dis(const int* __restrict__ deg, float* dis, int n) {
    int i = blockIdx.x * blockDim.x + threadIdx.x;
    if (i < n) dis[i] = rsqrtf((float)deg[i]);
}

// ---------------- hierarchical scan: offs = exclusive prefix of (deg-1) ----------------
#define SCAN_B 1024
#define SCAN_NB ((NN + SCAN_B - 1) / SCAN_B)  // 98

__global__ void k_scan1(const int* __restrict__ deg, int* __restrict__ part, int n) {
    __shared__ int ls[SCAN_B];
    int i = blockIdx.x * SCAN_B + threadIdx.x;
    ls[threadIdx.x] = (i < n) ? deg[i] - 1 : 0;
    __syncthreads();
    for (int d = SCAN_B / 2; d > 0; d >>= 1) {
        if (threadIdx.x < d) ls[threadIdx.x] += ls[threadIdx.x + d];
        __syncthreads();
    }
    if (threadIdx.x == 0) part[blockIdx.x] = ls[0];
}

__global__ void k_scan2(int* part, int* offs_last, int nb) {
    if (threadIdx.x == 0) {
        int run = 0;
        for (int b = 0; b < nb; b++) { int v = part[b]; part[b] = run; run += v; }
        offs_last[0] = run;  // == E
    }
}

__global__ void k_scan3(const int* __restrict__ deg, const int* __restrict__ part,
                        int* __restrict__ offs, int* __restrict__ cur, int n) {
    __shared__ int ls[SCAN_B];
    int i = blockIdx.x * SCAN_B + threadIdx.x;
    int v = (i < n) ? deg[i] - 1 : 0;
    ls[threadIdx.x] = v;
    __syncthreads();
    for (int d = 1; d < SCAN_B; d <<= 1) {
        int t = (threadIdx.x >= d) ? ls[threadIdx.x - d] : 0;
        __syncthreads();
        ls[threadIdx.x] += t;
        __syncthreads();
    }
    if (i < n) {
        int ex = part[blockIdx.x] + ls[threadIdx.x] - v;
        offs[i] = ex;
        cur[i] = ex;
    }
}

__global__ void k_fill(const int* __restrict__ src, const int* __restrict__ dst, int e,
                       const float* __restrict__ dis, int* cursor,
                       int* __restrict__ csrc, float* __restrict__ cw) {
    for (int i = blockIdx.x * blockDim.x + threadIdx.x; i < e; i += gridDim.x * blockDim.x) {
        int d = dst[i];
        int s = src[i];
        int p = atomicAdd(&cursor[d], 1);
        csrc[p] = s;
        cw[p] = dis[s] * dis[d];
    }
}

// transpose+cast weights: Wt[n*K+k] = bf16(W[k*N+n])
__global__ void k_wt(const float* __restrict__ W, unsigned short* __restrict__ Wt,
                     int K, int N) {
    int i = blockIdx.x * blockDim.x + threadIdx.x;
    if (i < K * N) {
        int n = i / K;
        int k = i - n * K;
        Wt[i] = f2bf(W[(size_t)k * N + n]);
    }
}

// ---------------- bf16 MFMA GEMM, m97-style global_load_lds staging -------------
// C[M,Nd](bf16) = A @ Bt^T + bias.  BM=128, BK=32, 4 waves (2x2).
// Single-buffer LDS, 2 barriers/K-step; staging via global_load_lds (loads stay
// in flight until the barrier's vmcnt(0) drain). Bank-conflict fix: XOR-swizzle
// the SOURCE chunk index (LDS stays linear in lane order), same XOR on ds_read.
// A f32 tile: chunk c^= (r&7)  (8x 16B chunks/row); bf16 tiles: c^= ((r>>1)&3).
template <int AF32, int BN_, int STATS>
__global__ __launch_bounds__(256) void k_gemm_mfma(
    const void* __restrict__ Av, const unsigned short* __restrict__ Bt,
    const float* __restrict__ bias, unsigned short* __restrict__ Cb,
    float* __restrict__ sum, float* __restrict__ sumsq,
    int M, int K, int Nd) {
    constexpr int NREP = BN_ / 32;
    constexpr int ACH = AF32 ? 8 : 4;        // 16B chunks per A-tile row
    constexpr int AOPS = AF32 ? 4 : 2;       // staging ops/thread for A
    constexpr int ASZ = AF32 ? 16384 : 8192;
    __shared__ __align__(16) unsigned char Asb[ASZ];
    __shared__ __align__(16) unsigned char Bsb[BN_ * 64];
    const int tid = threadIdx.x;
    const int lane = tid & 63;
    const int wid = tid >> 6;
    const int wrow = wid >> 1, wcol = wid & 1;
    const int row_base = blockIdx.y * 128;
    const int col_base = blockIdx.x * BN_;
    const unsigned char* Abase = (const unsigned char*)Av;
    const size_t arowb = (size_t)K * (AF32 ? 4 : 2);

    f32x4 acc[4][NREP];
#pragma unroll
    for (int m = 0; m < 4; m++)
#pragma unroll
        for (int n = 0; n < NREP; n++)
#pragma unroll
            for (int j = 0; j < 4; j++) acc[m][n][j] = 0.f;

    for (int kt = 0; kt < K; kt += 32) {
        // ---- stage A (rows clamped at M-1; extra rows feed unused outputs) ----
#pragma unroll
        for (int i = 0; i < AOPS; ++i) {
            int e = i * 256 + tid;
            int r = e / ACH;
            int c = e % ACH;
            int cs = AF32 ? (c ^ (r & 7)) : (c ^ ((r >> 1) & 3));
            int grow = row_base + r;
            if (grow > M - 1) grow = M - 1;
            const void* g = Abase + (size_t)grow * arowb + (size_t)kt * (AF32 ? 4 : 2) + (cs << 4);
            gl2lds16(g, Asb + e * 16);
        }
        // ---- stage B ----
#pragma unroll
        for (int i = 0; i < BN_ / 64; ++i) {
            int e = i * 256 + tid;
            int r = e >> 2, c = e & 3;
            int cs = c ^ ((r >> 1) & 3);
            const void* g = (const unsigned char*)Bt + (size_t)(col_base + r) * (K * 2) +
                            (size_t)kt * 2 + (cs << 4);
            gl2lds16(g, Bsb + e * 16);
        }
        __syncthreads();  // vmcnt(0)+lgkmcnt(0) drain: staged data visible

        bf16x8 af[4], bfr[NREP];
#pragma unroll
        for (int m = 0; m < 4; ++m) {
            int r = wrow * 64 + m * 16 + (lane & 15);
            if (AF32) {
                int x7 = r & 7;
                int q2 = (lane >> 4) * 2;
                f32x4 f0 = *(const f32x4*)(Asb + r * 128 + ((q2 ^ x7) << 4));
                f32x4 f1 = *(const f32x4*)(Asb + r * 128 + (((q2 + 1) ^ x7) << 4));
                bf16x8 a;
                a[0] = (__bf16)f0[0]; a[1] = (__bf16)f0[1]; a[2] = (__bf16)f0[2]; a[3] = (__bf16)f0[3];
                a[4] = (__bf16)f1[0]; a[5] = (__bf16)f1[1]; a[6] = (__bf16)f1[2]; a[7] = (__bf16)f1[3];
                af[m] = a;
            } else {
                int cs = (lane >> 4) ^ ((r >> 1) & 3);
                af[m] = *(const bf16x8*)(Asb + r * 64 + (cs << 4));
            }
        }
#pragma unroll
        for (int n = 0; n < NREP; ++n) {
            int r = wcol * (BN_ / 2) + n * 16 + (lane & 15);
            int cs = (lane >> 4) ^ ((r >> 1) & 3);
            bfr[n] = *(const bf16x8*)(Bsb + r * 64 + (cs << 4));
        }
#pragma unroll
        for (int m = 0; m < 4; ++m)
#pragma unroll
            for (int n = 0; n < NREP; ++n)
                acc[m][n] = __builtin_amdgcn_mfma_f32_16x16x32_bf16(af[m], bfr[n], acc[m][n], 0, 0, 0);
        __syncthreads();  // protect LDS before next stage overwrites
    }

    // epilogue: C/D mapping col=lane&15, row=(lane>>4)*4+j
    const int lc = lane & 15;
    const int lr = (lane >> 4) * 4;
#pragma unroll
    for (int m = 0; m < 4; ++m) {
        int gr0 = row_base + wrow * 64 + m * 16 + lr;
#pragma unroll
        for (int n = 0; n < NREP; ++n) {
            int gc = col_base + wcol * (BN_ / 2) + n * 16 + lc;
            float bb = bias[gc];
#pragma unroll
            for (int j = 0; j < 4; ++j) {
                int gr = gr0 + j;
                if (gr < M) Cb[(size_t)gr * Nd + gc] = f2bf(acc[m][n][j] + bb);
            }
        }
    }
    if (STATS) {
#pragma unroll
        for (int n = 0; n < NREP; ++n) {
            int gc = col_base + wcol * (BN_ / 2) + n * 16 + lc;
            float bb = bias[gc];
            float s = 0.f, s2 = 0.f;
#pragma unroll
            for (int m = 0; m < 4; ++m) {
                int gr0 = row_base + wrow * 64 + m * 16 + lr;
#pragma unroll
                for (int j = 0; j < 4; ++j) {
                    if (gr0 + j < M) {
                        float v = acc[m][n][j] + bb;
                        s += v;
                        s2 += v * v;
                    }
                }
            }
            s += __shfl_xor(s, 16); s += __shfl_xor(s, 32);
            s2 += __shfl_xor(s2, 16); s2 += __shfl_xor(s2, 32);
            if ((lane >> 4) == 0) {
                atomicAdd(&sum[gc], s);
                atomicAdd(&sumsq[gc], s2);
            }
        }
    }
}

__global__ void k_bnfin(const float* __restrict__ sum, const float* __restrict__ sq,
                        const float* __restrict__ g, const float* __restrict__ be,
                        float* scale, float* shift) {
    int c = threadIdx.x;
    float mu = sum[c] * (1.f / NN);
    float var = sq[c] * (1.f / NN) - mu * mu;
    float sc = g[c] * rsqrtf(var + BN_EPS);
    scale[c] = sc;
    shift[c] = be[c] - mu * sc;
}

// BN apply + ReLU, in place on bf16 [n][256]
__global__ void k_bnapply(unsigned short* __restrict__ h, const float* __restrict__ scale,
                          const float* __restrict__ shift, int n) {
    int total = n * 32;  // ushort8 groups
    for (int idx = blockIdx.x * blockDim.x + threadIdx.x; idx < total;
         idx += gridDim.x * blockDim.x) {
        int c8 = (idx & 31) * 8;
        ushort8v v = *(ushort8v*)(h + (size_t)idx * 8);
        f32x4 s0 = *(const f32x4*)(scale + c8);
        f32x4 s1 = *(const f32x4*)(scale + c8 + 4);
        f32x4 h0 = *(const f32x4*)(shift + c8);
        f32x4 h1 = *(const f32x4*)(shift + c8 + 4);
#pragma unroll
        for (int j = 0; j < 4; j++) {
            v[j] = f2bf(fmaxf(bf2f(v[j]) * s0[j] + h0[j], 0.f));
            v[j + 4] = f2bf(fmaxf(bf2f(v[j + 4]) * s1[j] + h1[j], 0.f));
        }
        *(ushort8v*)(h + (size_t)idx * 8) = v;
    }
}

// ---------------- propagation ----------------
// one wave per node; four 16-lane quarters each take every-4th neighbor with
// uint2 (4-channel) loads; combined via shfl_xor(16|32). 2x unrolled for ILP.
__global__ void k_hop(const unsigned short* __restrict__ xin,
                      unsigned short* __restrict__ xout,
                      const int* __restrict__ offs, const int* __restrict__ csrc,
                      const float* __restrict__ cw, const float* __restrict__ dis,
                      int n) {
    int wid = (int)((blockIdx.x * (size_t)blockDim.x + threadIdx.x) >> 6);
    if (wid >= n) return;
    int lane = threadIdx.x & 63;
    int q = lane >> 4;
    int l = lane & 15;
    const uint2* x8 = (const uint2*)xin;  // row = 16 uint2 (64 bf16)
    float y0 = 0.f, y1 = 0.f, y2 = 0.f, y3 = 0.f;
    if (q == 0) {
        float dn = dis[wid];
        float w = dn * dn;
        uint2 v = x8[(size_t)wid * 16 + l];
        y0 = w * bf2f((unsigned short)(v.x & 0xFFFF));
        y1 = w * bf2f((unsigned short)(v.x >> 16));
        y2 = w * bf2f((unsigned short)(v.y & 0xFFFF));
        y3 = w * bf2f((unsigned short)(v.y >> 16));
    }
    int p0 = offs[wid], p1 = offs[wid + 1];
    int p = p0 + q;
    for (; p + 4 < p1; p += 8) {
        int sA = csrc[p], sB = csrc[p + 4];
        float wA = cw[p], wB = cw[p + 4];
        uint2 vA = x8[(size_t)sA * 16 + l];
        uint2 vB = x8[(size_t)sB * 16 + l];
        y0 += wA * bf2f((unsigned short)(vA.x & 0xFFFF));
        y1 += wA * bf2f((unsigned short)(vA.x >> 16));
        y2 += wA * bf2f((unsigned short)(vA.y & 0xFFFF));
        y3 += wA * bf2f((unsigned short)(vA.y >> 16));
        y0 += wB * bf2f((unsigned short)(vB.x & 0xFFFF));
        y1 += wB * bf2f((unsigned short)(vB.x >> 16));
        y2 += wB * bf2f((unsigned short)(vB.y & 0xFFFF));
        y3 += wB * bf2f((unsigned short)(vB.y >> 16));
    }
    for (; p < p1; p += 4) {
        int s = csrc[p];
        float w = cw[p];
        uint2 v = x8[(size_t)s * 16 + l];
        y0 += w * bf2f((unsigned short)(v.x & 0xFFFF));
        y1 += w * bf2f((unsigned short)(v.x >> 16));
        y2 += w * bf2f((unsigned short)(v.y & 0xFFFF));
        y3 += w * bf2f((unsigned short)(v.y >> 16));
    }
#pragma unroll
    for (int m = 16; m <= 32; m <<= 1) {
        y0 += __shfl_xor(y0, m);
        y1 += __shfl_xor(y1, m);
        y2 += __shfl_xor(y2, m);
        y3 += __shfl_xor(y3, m);
    }
    if (q == 0) {
        uint2 r;
        r.x = ((unsigned)f2bf(y1) << 16) | (unsigned)f2bf(y0);
        r.y = ((unsigned)f2bf(y3) << 16) | (unsigned)f2bf(y2);
        ((uint2*)xout)[(size_t)wid * 16 + l] = r;
    }
}

struct XPack { const unsigned short* p[KHOPS + 1]; };

// two nodes per wave (one per 32-lane half), uint loads, 32-lane reductions
__global__ void k_finprop(XPack xp, const float* __restrict__ pw,
                          const float* __restrict__ pbp, float* __restrict__ out, int n) {
    int gw = (int)((blockIdx.x * (size_t)blockDim.x + threadIdx.x) >> 6);
    int lane = threadIdx.x & 63;
    int hf = lane >> 5;
    int l = lane & 31;
    int node = gw * 2 + hf;
    if (node >= n) return;
    float pw0 = pw[2 * l], pw1 = pw[2 * l + 1];
    float pb0 = pbp[0];
    float o0 = 0.f, o1 = 0.f;
#pragma unroll
    for (int k = 0; k <= KHOPS; k++) {
        unsigned v = ((const unsigned*)xp.p[k])[(size_t)node * 32 + l];
        float v0 = bf2f((unsigned short)(v & 0xFFFF));
        float v1 = bf2f((unsigned short)(v >> 16));
        float d = v0 * pw0 + v1 * pw1;
#pragma unroll
        for (int m = 16; m >= 1; m >>= 1) d += __shfl_xor(d, m);
        float s = 1.f / (1.f + expf(-(d + pb0)));
        o0 += s * v0;
        o1 += s * v1;
    }
    float mx = fmaxf(o0, o1);
#pragma unroll
    for (int m = 16; m >= 1; m >>= 1) mx = fmaxf(mx, __shfl_xor(mx, m));
    float e = expf(o0 - mx) + expf(o1 - mx);
#pragma unroll
    for (int m = 16; m >= 1; m >>= 1) e += __shfl_xor(e, m);
    float lg = mx + logf(e);
    float2 r = make_float2(o0 - lg, o1 - lg);
    *(float2*)(out + (size_t)node * 64 + 2 * l) = r;
}

// ---------------- launch ----------------
extern "C" void kernel_launch(void* const* d_in, const int* in_sizes, int n_in,
                              void* d_out, int out_size, void* d_ws, size_t ws_size,
                              hipStream_t stream) {
    const float* x  = (const float*)d_in[0];
    const float* W0 = (const float*)d_in[1];
    const float* b0 = (const float*)d_in[2];
    const float* g0 = (const float*)d_in[3];
    const float* be0 = (const float*)d_in[4];
    const float* W1 = (const float*)d_in[5];
    const float* b1 = (const float*)d_in[6];
    const float* g1 = (const float*)d_in[7];
    const float* be1 = (const float*)d_in[8];
    const float* W2 = (const float*)d_in[9];
    const float* b2 = (const float*)d_in[10];
    const float* pw = (const float*)d_in[11];
    const float* pb = (const float*)d_in[12];
    const int* ei = (const int*)d_in[13];
    const int E = in_sizes[13] / 2;
    const int* esrc = ei;
    const int* edst = ei + E;

    char* ws = (char*)d_ws;
    const size_t XKB = (size_t)NN * CC * 2;  // 12,800,000 B per hop buffer
    unsigned short* h0b = (unsigned short*)(ws + 0);          // [N,256] bf16 (pre/post BN)
    unsigned short* h1b = (unsigned short*)(ws + 51200000);   // [N,256] bf16
    unsigned short* xk[KHOPS + 1];
    xk[0] = (unsigned short*)(ws + 0);                         // over h0b (dead after gemm1)
    xk[5] = (unsigned short*)(ws + XKB);
    xk[6] = (unsigned short*)(ws + 2 * XKB);
    xk[7] = (unsigned short*)(ws + 3 * XKB);
    xk[1] = (unsigned short*)(ws + 51200000);                  // over h1b (dead after gemm2)
    xk[2] = (unsigned short*)(ws + 51200000 + XKB);
    xk[3] = (unsigned short*)(ws + 51200000 + 2 * XKB);
    xk[4] = (unsigned short*)(ws + 51200000 + 3 * XKB);
    xk[8] = (unsigned short*)(ws + 102400000);
    xk[9] = (unsigned short*)(ws + 115200000);
    xk[10] = (unsigned short*)(ws + 128000000);

    int*   deg  = (int*)  (ws + 140800000);
    float* dis  = (float*)(ws + 141200000);
    int*   offs = (int*)  (ws + 141600000);   // NN+1 ints
    int*   cur  = (int*)  (ws + 142000064);
    int*   csrc = (int*)  (ws + 142400064);
    float* cw   = (float*)(ws + 148800064);
    float* stats = (float*)(ws + 155200064);  // 2048 f32
    int*   part = (int*)  (ws + 155208256);   // scan partials
    unsigned short* W0t = (unsigned short*)(ws + 155209280);  // [256,512]
    unsigned short* W1t = (unsigned short*)(ws + 155471424);  // [256,256]
    unsigned short* W2t = (unsigned short*)(ws + 155602496);  // [64,256]

    float* sum0 = stats,        *sq0 = stats + 256;
    float* sum1 = stats + 512,  *sq1 = stats + 768;
    float* scale0 = stats + 1024, *shift0 = stats + 1280;
    float* scale1 = stats + 1536, *shift1 = stats + 1792;

    float* out = (float*)d_out;

    const int TPB = 256;
    int ngrid = (NN + TPB - 1) / TPB;
    int egrid = (E + TPB - 1) / TPB;
    int wgrid = (NN * 64 + TPB - 1) / TPB;       // one wave per node
    int wgrid2 = (((NN + 1) / 2) * 64 + TPB - 1) / TPB;  // two nodes per wave
    int mtiles = (NN + 127) / 128;               // 782

    // graph preprocessing
    k_zero<<<2, 1024, 0, stream>>>(stats, 2048);
    k_deg_init<<<ngrid, TPB, 0, stream>>>(deg, NN);
    k_deg_count<<<egrid, TPB, 0, stream>>>(edst, E, deg);
    k_dis<<<ngrid, TPB, 0, stream>>>(deg, dis, NN);
    k_scan1<<<SCAN_NB, SCAN_B, 0, stream>>>(deg, part, NN);
    k_scan2<<<1, 64, 0, stream>>>(part, offs + NN, SCAN_NB);
    k_scan3<<<SCAN_NB, SCAN_B, 0, stream>>>(deg, part, offs, cur, NN);
    k_fill<<<egrid, TPB, 0, stream>>>(esrc, edst, E, dis, cur, csrc, cw);

    // weight transpose+cast (tiny)
    k_wt<<<(FF * HH + TPB - 1) / TPB, TPB, 0, stream>>>(W0, W0t, FF, HH);
    k_wt<<<(HH * HH + TPB - 1) / TPB, TPB, 0, stream>>>(W1, W1t, HH, HH);
    k_wt<<<(HH * CC + TPB - 1) / TPB, TPB, 0, stream>>>(W2, W2t, HH, CC);

    // layer 0: x(f32) @ W0 -> h0b (pre-BN bf16) + stats0
    k_gemm_mfma<1, 128, 1><<<dim3(HH / 128, mtiles), 256, 0, stream>>>(
        x, W0t, b0, h0b, sum0, sq0, NN, FF, HH);
    k_bnfin<<<1, 256, 0, stream>>>(sum0, sq0, g0, be0, scale0, shift0);
    k_bnapply<<<2048, TPB, 0, stream>>>(h0b, scale0, shift0, NN);

    // layer 1: h0b @ W1 -> h1b (pre-BN bf16) + stats1
    k_gemm_mfma<0, 128, 1><<<dim3(HH / 128, mtiles), 256, 0, stream>>>(
        h0b, W1t, b1, h1b, sum1, sq1, NN, HH, HH);
    k_bnfin<<<1, 256, 0, stream>>>(sum1, sq1, g1, be1, scale1, shift1);
    k_bnapply<<<2048, TPB, 0, stream>>>(h1b, scale1, shift1, NN);

    // layer 2: h1b @ W2 -> xk0 (bf16 logits)
    k_gemm_mfma<0, 64, 0><<<dim3(1, mtiles), 256, 0, stream>>>(
        h1b, W2t, b2, xk[0], nullptr, nullptr, NN, HH, CC);

    // propagation: xk[k+1] = Ahat xk[k]
    for (int k = 0; k < KHOPS; k++)
        k_hop<<<wgrid, TPB, 0, stream>>>(xk[k], xk[k + 1], offs, csrc, cw, dis, NN);

    // fused score + weighted-sum + log-softmax
    XPack xp;
    for (int k = 0; k <= KHOPS; k++) xp.p[k] = xk[k];
    k_finprop<<<wgrid2, TPB, 0, stream>>>(xp, pw, pb, out, NN);
}

// Round 6
// 887.027 us; speedup vs baseline: 3.3786x; 1.0760x over previous
//
#include <hip/hip_runtime.h>
#include <hip/hip_bf16.h>
#include <math.h>

// Problem constants (from reference)
#define NN 100000
#define FF 512
#define HH 256
#define CC 64
#define KHOPS 10
#define BN_EPS 1e-5f

typedef __bf16 bf16x8 __attribute__((ext_vector_type(8)));
typedef float f32x4 __attribute__((ext_vector_type(4)));
typedef unsigned short ushort8v __attribute__((ext_vector_type(8)));

__device__ __forceinline__ unsigned short f2bf(float f) {
    __bf16 b = (__bf16)f;  // v_cvt RNE
    return __builtin_bit_cast(unsigned short, b);
}
__device__ __forceinline__ float bf2f(unsigned short h) {
    unsigned u = ((unsigned)h) << 16;
    return __builtin_bit_cast(float, u);
}
__device__ __forceinline__ float lo16(unsigned u) { return bf2f((unsigned short)(u & 0xFFFF)); }
__device__ __forceinline__ float hi16(unsigned u) { return bf2f((unsigned short)(u >> 16)); }
__device__ __forceinline__ unsigned pk(float a, float b) {
    return ((unsigned)f2bf(b) << 16) | (unsigned)f2bf(a);
}

// async global->LDS, 16B per lane.
typedef __attribute__((address_space(1))) const void g_void;
typedef __attribute__((address_space(3))) void l_void;
__device__ __forceinline__ void gl2lds16(const void* g, void* l) {
    __builtin_amdgcn_global_load_lds((g_void*)g, (l_void*)l, 16, 0, 0);
}

// ---------------- utility kernels ----------------
__global__ void k_zero(float* p, int n) {
    int i = blockIdx.x * blockDim.x + threadIdx.x;
    if (i < n) p[i] = 0.f;
}

__global__ void k_deg_init(int* deg, int n) {
    int i = blockIdx.x * blockDim.x + threadIdx.x;
    if (i < n) deg[i] = 1;  // self-loop
}

__global__ void k_deg_count(const int* __restrict__ dst, int e, int* deg) {
    for (int i = blockIdx.x * blockDim.x + threadIdx.x; i < e; i += gridDim.x * blockDim.x)
        atomicAdd(&deg[dst[i]], 1);
}

__global__ void k_dis(const int* __restrict__ deg, float* dis, int n) {
    int i = blockIdx.x * blockDim.x + threadIdx.x;
    if (i < n) dis[i] = rsqrtf((float)deg[i]);
}

// ---------------- hierarchical scan: offs = exclusive prefix of (deg-1) ----------------
#define SCAN_B 1024
#define SCAN_NB ((NN + SCAN_B - 1) / SCAN_B)  // 98

__global__ void k_scan1(const int* __restrict__ deg, int* __restrict__ part, int n) {
    __shared__ int ls[SCAN_B];
    int i = blockIdx.x * SCAN_B + threadIdx.x;
    ls[threadIdx.x] = (i < n) ? deg[i] - 1 : 0;
    __syncthreads();
    for (int d = SCAN_B / 2; d > 0; d >>= 1) {
        if (threadIdx.x < d) ls[threadIdx.x] += ls[threadIdx.x + d];
        __syncthreads();
    }
    if (threadIdx.x == 0) part[blockIdx.x] = ls[0];
}

__global__ void k_scan2(int* part, int* offs_last, int nb) {
    if (threadIdx.x == 0) {
        int run = 0;
        for (int b = 0; b < nb; b++) { int v = part[b]; part[b] = run; run += v; }
        offs_last[0] = run;  // == E
    }
}

__global__ void k_scan3(const int* __restrict__ deg, const int* __restrict__ part,
                        int* __restrict__ offs, int* __restrict__ cur, int n) {
    __shared__ int ls[SCAN_B];
    int i = blockIdx.x * SCAN_B + threadIdx.x;
    int v = (i < n) ? deg[i] - 1 : 0;
    ls[threadIdx.x] = v;
    __syncthreads();
    for (int d = 1; d < SCAN_B; d <<= 1) {
        int t = (threadIdx.x >= d) ? ls[threadIdx.x - d] : 0;
        __syncthreads();
        ls[threadIdx.x] += t;
        __syncthreads();
    }
    if (i < n) {
        int ex = part[blockIdx.x] + ls[threadIdx.x] - v;
        offs[i] = ex;
        cur[i] = ex;
    }
}

__global__ void k_fill(const int* __restrict__ src, const int* __restrict__ dst, int e,
                       const float* __restrict__ dis, int* cursor,
                       int* __restrict__ csrc, float* __restrict__ cw) {
    for (int i = blockIdx.x * blockDim.x + threadIdx.x; i < e; i += gridDim.x * blockDim.x) {
        int d = dst[i];
        int s = src[i];
        int p = atomicAdd(&cursor[d], 1);
        csrc[p] = s;
        cw[p] = dis[s] * dis[d];
    }
}

// transpose+cast weights: Wt[n*K+k] = bf16(W[k*N+n])
__global__ void k_wt(const float* __restrict__ W, unsigned short* __restrict__ Wt,
                     int K, int N) {
    int i = blockIdx.x * blockDim.x + threadIdx.x;
    if (i < K * N) {
        int n = i / K;
        int k = i - n * K;
        Wt[i] = f2bf(W[(size_t)k * N + n]);
    }
}

// ---------------- bf16 MFMA GEMM, global_load_lds staging -------------
// C[M,Nd](bf16) = A @ Bt^T + bias.  BM=128, BK=32, NW waves.
// NW=8: 2x4 wave grid (512 thr), per-wave 64x(BN_/4). NW=4: 2x2, 64x(BN_/2).
// Single-buffer LDS, 2 barriers/K-step; source-XOR swizzle (LDS linear).
template <int AF32, int BN_, int STATS, int NW>
__global__ __launch_bounds__(NW * 64) void k_gemm_mfma(
    const void* __restrict__ Av, const unsigned short* __restrict__ Bt,
    const float* __restrict__ bias, unsigned short* __restrict__ Cb,
    float* __restrict__ sum, float* __restrict__ sumsq,
    int M, int K, int Nd) {
    constexpr int NT = NW * 64;
    constexpr int WC = (NW == 8) ? 4 : 2;       // wave cols
    constexpr int PWN = BN_ / WC;               // per-wave N
    constexpr int NREP = PWN / 16;
    constexpr int ACH = AF32 ? 8 : 4;           // 16B chunks per A row
    constexpr int AOPS = 128 * ACH / NT;
    constexpr int BOPS = BN_ * 4 / NT;
    constexpr int ASZ = AF32 ? 16384 : 8192;
    __shared__ __align__(16) unsigned char Asb[ASZ];
    __shared__ __align__(16) unsigned char Bsb[BN_ * 64];
    const int tid = threadIdx.x;
    const int lane = tid & 63;
    const int wid = tid >> 6;
    const int wrow = wid / WC, wcol = wid % WC;
    const int row_base = blockIdx.y * 128;
    const int col_base = blockIdx.x * BN_;
    const unsigned char* Abase = (const unsigned char*)Av;
    const size_t arowb = (size_t)K * (AF32 ? 4 : 2);

    f32x4 acc[4][NREP];
#pragma unroll
    for (int m = 0; m < 4; m++)
#pragma unroll
        for (int n = 0; n < NREP; n++)
#pragma unroll
            for (int j = 0; j < 4; j++) acc[m][n][j] = 0.f;

    for (int kt = 0; kt < K; kt += 32) {
        // ---- stage A (rows clamped at M-1; extra rows feed unused outputs) ----
#pragma unroll
        for (int i = 0; i < AOPS; ++i) {
            int e = i * NT + tid;
            int r = e / ACH;
            int c = e % ACH;
            int cs = AF32 ? (c ^ (r & 7)) : (c ^ ((r >> 1) & 3));
            int grow = row_base + r;
            if (grow > M - 1) grow = M - 1;
            const void* g = Abase + (size_t)grow * arowb + (size_t)kt * (AF32 ? 4 : 2) + (cs << 4);
            gl2lds16(g, Asb + e * 16);
        }
        // ---- stage B ----
#pragma unroll
        for (int i = 0; i < BOPS; ++i) {
            int e = i * NT + tid;
            int r = e >> 2, c = e & 3;
            int cs = c ^ ((r >> 1) & 3);
            const void* g = (const unsigned char*)Bt + (size_t)(col_base + r) * (K * 2) +
                            (size_t)kt * 2 + (cs << 4);
            gl2lds16(g, Bsb + e * 16);
        }
        __syncthreads();  // vmcnt(0)+lgkmcnt(0) drain: staged data visible

        bf16x8 af[4], bfr[NREP];
#pragma unroll
        for (int m = 0; m < 4; ++m) {
            int r = wrow * 64 + m * 16 + (lane & 15);
            if (AF32) {
                int x7 = r & 7;
                int q2 = (lane >> 4) * 2;
                f32x4 f0 = *(const f32x4*)(Asb + r * 128 + ((q2 ^ x7) << 4));
                f32x4 f1 = *(const f32x4*)(Asb + r * 128 + (((q2 + 1) ^ x7) << 4));
                bf16x8 a;
                a[0] = (__bf16)f0[0]; a[1] = (__bf16)f0[1]; a[2] = (__bf16)f0[2]; a[3] = (__bf16)f0[3];
                a[4] = (__bf16)f1[0]; a[5] = (__bf16)f1[1]; a[6] = (__bf16)f1[2]; a[7] = (__bf16)f1[3];
                af[m] = a;
            } else {
                int cs = (lane >> 4) ^ ((r >> 1) & 3);
                af[m] = *(const bf16x8*)(Asb + r * 64 + (cs << 4));
            }
        }
#pragma unroll
        for (int n = 0; n < NREP; ++n) {
            int r = wcol * PWN + n * 16 + (lane & 15);
            int cs = (lane >> 4) ^ ((r >> 1) & 3);
            bfr[n] = *(const bf16x8*)(Bsb + r * 64 + (cs << 4));
        }
#pragma unroll
        for (int m = 0; m < 4; ++m)
#pragma unroll
            for (int n = 0; n < NREP; ++n)
                acc[m][n] = __builtin_amdgcn_mfma_f32_16x16x32_bf16(af[m], bfr[n], acc[m][n], 0, 0, 0);
        __syncthreads();  // protect LDS before next stage overwrites
    }

    // epilogue: C/D mapping col=lane&15, row=(lane>>4)*4+j
    const int lc = lane & 15;
    const int lr = (lane >> 4) * 4;
#pragma unroll
    for (int m = 0; m < 4; ++m) {
        int gr0 = row_base + wrow * 64 + m * 16 + lr;
#pragma unroll
        for (int n = 0; n < NREP; ++n) {
            int gc = col_base + wcol * PWN + n * 16 + lc;
            float bb = bias[gc];
#pragma unroll
            for (int j = 0; j < 4; ++j) {
                int gr = gr0 + j;
                if (gr < M) Cb[(size_t)gr * Nd + gc] = f2bf(acc[m][n][j] + bb);
            }
        }
    }
    if (STATS) {
#pragma unroll
        for (int n = 0; n < NREP; ++n) {
            int gc = col_base + wcol * PWN + n * 16 + lc;
            float bb = bias[gc];
            float s = 0.f, s2 = 0.f;
#pragma unroll
            for (int m = 0; m < 4; ++m) {
                int gr0 = row_base + wrow * 64 + m * 16 + lr;
#pragma unroll
                for (int j = 0; j < 4; ++j) {
                    if (gr0 + j < M) {
                        float v = acc[m][n][j] + bb;
                        s += v;
                        s2 += v * v;
                    }
                }
            }
            s += __shfl_xor(s, 16); s += __shfl_xor(s, 32);
            s2 += __shfl_xor(s2, 16); s2 += __shfl_xor(s2, 32);
            if ((lane >> 4) == 0) {
                atomicAdd(&sum[gc], s);
                atomicAdd(&sumsq[gc], s2);
            }
        }
    }
}

__global__ void k_bnfin(const float* __restrict__ sum, const float* __restrict__ sq,
                        const float* __restrict__ g, const float* __restrict__ be,
                        float* scale, float* shift) {
    int c = threadIdx.x;
    float mu = sum[c] * (1.f / NN);
    float var = sq[c] * (1.f / NN) - mu * mu;
    float sc = g[c] * rsqrtf(var + BN_EPS);
    scale[c] = sc;
    shift[c] = be[c] - mu * sc;
}

// BN apply + ReLU, in place on bf16 [n][256]
__global__ void k_bnapply(unsigned short* __restrict__ h, const float* __restrict__ scale,
                          const float* __restrict__ shift, int n) {
    int total = n * 32;  // ushort8 groups
    for (int idx = blockIdx.x * blockDim.x + threadIdx.x; idx < total;
         idx += gridDim.x * blockDim.x) {
        int c8 = (idx & 31) * 8;
        ushort8v v = *(ushort8v*)(h + (size_t)idx * 8);
        f32x4 s0 = *(const f32x4*)(scale + c8);
        f32x4 s1 = *(const f32x4*)(scale + c8 + 4);
        f32x4 h0 = *(const f32x4*)(shift + c8);
        f32x4 h1 = *(const f32x4*)(shift + c8 + 4);
#pragma unroll
        for (int j = 0; j < 4; j++) {
            v[j] = f2bf(fmaxf(bf2f(v[j]) * s0[j] + h0[j], 0.f));
            v[j + 4] = f2bf(fmaxf(bf2f(v[j + 4]) * s1[j] + h1[j], 0.f));
        }
        *(ushort8v*)(h + (size_t)idx * 8) = v;
    }
}

// ---------------- propagation ----------------
// one wave per node; eight 8-lane groups each take every-8th neighbor with
// uint4 (8-channel) loads -> one load inst = 8 cache lines in flight.
__global__ void k_hop(const unsigned short* __restrict__ xin,
                      unsigned short* __restrict__ xout,
                      const int* __restrict__ offs, const int* __restrict__ csrc,
                      const float* __restrict__ cw, const float* __restrict__ dis,
                      int n) {
    int wid = (int)((blockIdx.x * (size_t)blockDim.x + threadIdx.x) >> 6);
    if (wid >= n) return;
    int lane = threadIdx.x & 63;
    int g = lane >> 3;   // group 0..7
    int j = lane & 7;    // 16B slot in row
    const uint4* x16 = (const uint4*)xin;  // row = 8 uint4 (64 bf16)
    float y0 = 0.f, y1 = 0.f, y2 = 0.f, y3 = 0.f, y4 = 0.f, y5 = 0.f, y6 = 0.f, y7 = 0.f;
    if (g == 0) {
        float dn = dis[wid];
        float w = dn * dn;
        uint4 v = x16[(size_t)wid * 8 + j];
        y0 = w * lo16(v.x); y1 = w * hi16(v.x);
        y2 = w * lo16(v.y); y3 = w * hi16(v.y);
        y4 = w * lo16(v.z); y5 = w * hi16(v.z);
        y6 = w * lo16(v.w); y7 = w * hi16(v.w);
    }
    int p0 = offs[wid], p1 = offs[wid + 1];
    int p = p0 + g;
    for (; p + 8 < p1; p += 16) {
        int sA = csrc[p], sB = csrc[p + 8];
        float wA = cw[p], wB = cw[p + 8];
        uint4 vA = x16[(size_t)sA * 8 + j];
        uint4 vB = x16[(size_t)sB * 8 + j];
        y0 += wA * lo16(vA.x); y1 += wA * hi16(vA.x);
        y2 += wA * lo16(vA.y); y3 += wA * hi16(vA.y);
        y4 += wA * lo16(vA.z); y5 += wA * hi16(vA.z);
        y6 += wA * lo16(vA.w); y7 += wA * hi16(vA.w);
        y0 += wB * lo16(vB.x); y1 += wB * hi16(vB.x);
        y2 += wB * lo16(vB.y); y3 += wB * hi16(vB.y);
        y4 += wB * lo16(vB.z); y5 += wB * hi16(vB.z);
        y6 += wB * lo16(vB.w); y7 += wB * hi16(vB.w);
    }
    for (; p < p1; p += 8) {
        int s = csrc[p];
        float w = cw[p];
        uint4 v = x16[(size_t)s * 8 + j];
        y0 += w * lo16(v.x); y1 += w * hi16(v.x);
        y2 += w * lo16(v.y); y3 += w * hi16(v.y);
        y4 += w * lo16(v.z); y5 += w * hi16(v.z);
        y6 += w * lo16(v.w); y7 += w * hi16(v.w);
    }
    // sum across the 8 groups (lane bits 3..5)
#pragma unroll
    for (int m = 8; m <= 32; m <<= 1) {
        y0 += __shfl_xor(y0, m); y1 += __shfl_xor(y1, m);
        y2 += __shfl_xor(y2, m); y3 += __shfl_xor(y3, m);
        y4 += __shfl_xor(y4, m); y5 += __shfl_xor(y5, m);
        y6 += __shfl_xor(y6, m); y7 += __shfl_xor(y7, m);
    }
    if (g == 0) {
        uint4 r;
        r.x = pk(y0, y1); r.y = pk(y2, y3); r.z = pk(y4, y5); r.w = pk(y6, y7);
        ((uint4*)xout)[(size_t)wid * 8 + j] = r;
    }
}

struct XPack { const unsigned short* p[KHOPS + 1]; };

// two nodes per wave (one per 32-lane half), uint loads, 32-lane reductions
__global__ void k_finprop(XPack xp, const float* __restrict__ pw,
                          const float* __restrict__ pbp, float* __restrict__ out, int n) {
    int gw = (int)((blockIdx.x * (size_t)blockDim.x + threadIdx.x) >> 6);
    int lane = threadIdx.x & 63;
    int hf = lane >> 5;
    int l = lane & 31;
    int node = gw * 2 + hf;
    if (node >= n) return;
    float pw0 = pw[2 * l], pw1 = pw[2 * l + 1];
    float pb0 = pbp[0];
    float o0 = 0.f, o1 = 0.f;
#pragma unroll
    for (int k = 0; k <= KHOPS; k++) {
        unsigned v = ((const unsigned*)xp.p[k])[(size_t)node * 32 + l];
        float v0 = lo16(v);
        float v1 = hi16(v);
        float d = v0 * pw0 + v1 * pw1;
#pragma unroll
        for (int m = 16; m >= 1; m >>= 1) d += __shfl_xor(d, m);
        float s = 1.f / (1.f + expf(-(d + pb0)));
        o0 += s * v0;
        o1 += s * v1;
    }
    float mx = fmaxf(o0, o1);
#pragma unroll
    for (int m = 16; m >= 1; m >>= 1) mx = fmaxf(mx, __shfl_xor(mx, m));
    float e = expf(o0 - mx) + expf(o1 - mx);
#pragma unroll
    for (int m = 16; m >= 1; m >>= 1) e += __shfl_xor(e, m);
    float lg = mx + logf(e);
    float2 r = make_float2(o0 - lg, o1 - lg);
    *(float2*)(out + (size_t)node * 64 + 2 * l) = r;
}

// ---------------- launch ----------------
extern "C" void kernel_launch(void* const* d_in, const int* in_sizes, int n_in,
                              void* d_out, int out_size, void* d_ws, size_t ws_size,
                              hipStream_t stream) {
    const float* x  = (const float*)d_in[0];
    const float* W0 = (const float*)d_in[1];
    const float* b0 = (const float*)d_in[2];
    const float* g0 = (const float*)d_in[3];
    const float* be0 = (const float*)d_in[4];
    const float* W1 = (const float*)d_in[5];
    const float* b1 = (const float*)d_in[6];
    const float* g1 = (const float*)d_in[7];
    const float* be1 = (const float*)d_in[8];
    const float* W2 = (const float*)d_in[9];
    const float* b2 = (const float*)d_in[10];
    const float* pw = (const float*)d_in[11];
    const float* pb = (const float*)d_in[12];
    const int* ei = (const int*)d_in[13];
    const int E = in_sizes[13] / 2;
    const int* esrc = ei;
    const int* edst = ei + E;

    char* ws = (char*)d_ws;
    const size_t XKB = (size_t)NN * CC * 2;  // 12,800,000 B per hop buffer
    unsigned short* h0b = (unsigned short*)(ws + 0);          // [N,256] bf16 (pre/post BN)
    unsigned short* h1b = (unsigned short*)(ws + 51200000);   // [N,256] bf16
    unsigned short* xk[KHOPS + 1];
    xk[0] = (unsigned short*)(ws + 0);                         // over h0b (dead after gemm1)
    xk[5] = (unsigned short*)(ws + XKB);
    xk[6] = (unsigned short*)(ws + 2 * XKB);
    xk[7] = (unsigned short*)(ws + 3 * XKB);
    xk[1] = (unsigned short*)(ws + 51200000);                  // over h1b (dead after gemm2)
    xk[2] = (unsigned short*)(ws + 51200000 + XKB);
    xk[3] = (unsigned short*)(ws + 51200000 + 2 * XKB);
    xk[4] = (unsigned short*)(ws + 51200000 + 3 * XKB);
    xk[8] = (unsigned short*)(ws + 102400000);
    xk[9] = (unsigned short*)(ws + 115200000);
    xk[10] = (unsigned short*)(ws + 128000000);

    int*   deg  = (int*)  (ws + 140800000);
    float* dis  = (float*)(ws + 141200000);
    int*   offs = (int*)  (ws + 141600000);   // NN+1 ints
    int*   cur  = (int*)  (ws + 142000064);
    int*   csrc = (int*)  (ws + 142400064);
    float* cw   = (float*)(ws + 148800064);
    float* stats = (float*)(ws + 155200064);  // 2048 f32
    int*   part = (int*)  (ws + 155208256);   // scan partials
    unsigned short* W0t = (unsigned short*)(ws + 155209280);  // [256,512]
    unsigned short* W1t = (unsigned short*)(ws + 155471424);  // [256,256]
    unsigned short* W2t = (unsigned short*)(ws + 155602496);  // [64,256]

    float* sum0 = stats,        *sq0 = stats + 256;
    float* sum1 = stats + 512,  *sq1 = stats + 768;
    float* scale0 = stats + 1024, *shift0 = stats + 1280;
    float* scale1 = stats + 1536, *shift1 = stats + 1792;

    float* out = (float*)d_out;

    const int TPB = 256;
    int ngrid = (NN + TPB - 1) / TPB;
    int egrid = (E + TPB - 1) / TPB;
    int wgrid = (NN * 64 + TPB - 1) / TPB;       // one wave per node
    int wgrid2 = (((NN + 1) / 2) * 64 + TPB - 1) / TPB;  // two nodes per wave
    int mtiles = (NN + 127) / 128;               // 782

    // graph preprocessing
    k_zero<<<2, 1024, 0, stream>>>(stats, 2048);
    k_deg_init<<<ngrid, TPB, 0, stream>>>(deg, NN);
    k_deg_count<<<egrid, TPB, 0, stream>>>(edst, E, deg);
    k_dis<<<ngrid, TPB, 0, stream>>>(deg, dis, NN);
    k_scan1<<<SCAN_NB, SCAN_B, 0, stream>>>(deg, part, NN);
    k_scan2<<<1, 64, 0, stream>>>(part, offs + NN, SCAN_NB);
    k_scan3<<<SCAN_NB, SCAN_B, 0, stream>>>(deg, part, offs, cur, NN);
    k_fill<<<egrid, TPB, 0, stream>>>(esrc, edst, E, dis, cur, csrc, cw);

    // weight transpose+cast (tiny)
    k_wt<<<(FF * HH + TPB - 1) / TPB, TPB, 0, stream>>>(W0, W0t, FF, HH);
    k_wt<<<(HH * HH + TPB - 1) / TPB, TPB, 0, stream>>>(W1, W1t, HH, HH);
    k_wt<<<(HH * CC + TPB - 1) / TPB, TPB, 0, stream>>>(W2, W2t, HH, CC);

    // layer 0: x(f32) @ W0 -> h0b (pre-BN bf16) + stats0.  BN=256: A staged once.
    k_gemm_mfma<1, 256, 1, 8><<<dim3(1, mtiles), 512, 0, stream>>>(
        x, W0t, b0, h0b, sum0, sq0, NN, FF, HH);
    k_bnfin<<<1, 256, 0, stream>>>(sum0, sq0, g0, be0, scale0, shift0);
    k_bnapply<<<2048, TPB, 0, stream>>>(h0b, scale0, shift0, NN);

    // layer 1: h0b @ W1 -> h1b (pre-BN bf16) + stats1
    k_gemm_mfma<0, 256, 1, 8><<<dim3(1, mtiles), 512, 0, stream>>>(
        h0b, W1t, b1, h1b, sum1, sq1, NN, HH, HH);
    k_bnfin<<<1, 256, 0, stream>>>(sum1, sq1, g1, be1, scale1, shift1);
    k_bnapply<<<2048, TPB, 0, stream>>>(h1b, scale1, shift1, NN);

    // layer 2: h1b @ W2 -> xk0 (bf16 logits)
    k_gemm_mfma<0, 64, 0, 4><<<dim3(1, mtiles), 256, 0, stream>>>(
        h1b, W2t, b2, xk[0], nullptr, nullptr, NN, HH, CC);

    // propagation: xk[k+1] = Ahat xk[k]
    for (int k = 0; k < KHOPS; k++)
        k_hop<<<wgrid, TPB, 0, stream>>>(xk[k], xk[k + 1], offs, csrc, cw, dis, NN);

    // fused score + weighted-sum + log-softmax
    XPack xp;
    for (int k = 0; k <= KHOPS; k++) xp.p[k] = xk[k];
    k_finprop<<<wgrid2, TPB, 0, stream>>>(xp, pw, pb, out, NN);
}